// Round 1
// baseline (4679.794 us; speedup 1.0000x reference)
//
#include <hip/hip_runtime.h>

#define N_NODES 50000
#define N_EDGES 800000
#define IN_F    128
#define OUT_F   128
#define NEIG    64
#define HDIM    128
#define XT_COLS 640
#define BN_EPSF 1e-5f

// ---- workspace layout (in floats) ----
#define OFF_XT     0
#define OFF_DSQRT  (N_NODES * XT_COLS)            // 32,000,000
#define OFF_HS     (OFF_DSQRT + N_NODES)          // 32,050,000
#define OFF_EF     (OFF_HS + NEIG * OUT_F)        // +8192
#define OFF_COLSUM (OFF_EF + NEIG)                // +64
#define OFF_COLSQ  (OFF_COLSUM + OUT_F)           // +128
// total = 32,058,512 floats ≈ 128.3 MB

// Zero deg (N floats) and the small stats region (hs_small..colsq, 8512 floats)
__global__ void k_zero(float* __restrict__ deg, float* __restrict__ small) {
    int i = blockIdx.x * 256 + threadIdx.x;
    if (i < N_NODES) deg[i] = 0.0f;
    if (i < NEIG * OUT_F + NEIG + 2 * OUT_F) small[i] = 0.0f;
}

// Xt cols 0..127 = feature ; cols 128..511 = 0 (scatter targets)
__global__ void k_init_xt(float* __restrict__ Xt, const float* __restrict__ feat) {
    int t = blockIdx.x * 256 + threadIdx.x;   // N*128 threads, c = float4 slot over 512 cols
    int n = t >> 7, c = t & 127;
    float4 v;
    if (c < 32) {
        v = *(const float4*)&feat[n * IN_F + c * 4];
    } else {
        v = make_float4(0.f, 0.f, 0.f, 0.f);
    }
    *(float4*)&Xt[n * XT_COLS + c * 4] = v;
}

__global__ void k_deg(float* __restrict__ deg, const int* __restrict__ dst) {
    int e = blockIdx.x * 256 + threadIdx.x;
    if (e < N_EDGES) atomicAdd(&deg[dst[e]], 1.0f);
}

__global__ void k_dsqrt(float* __restrict__ deg) {
    int n = blockIdx.x * 256 + threadIdx.x;
    if (n < N_NODES) {
        float d = deg[n];
        deg[n] = rsqrtf(fmaxf(d, 1.0f));
    }
}

// agg[dst, slot_off+*] += X[src, prev_off+*] * d_sqrt[src]
__global__ void k_scatter(float* __restrict__ Xt, int prev_off, int dst_off,
                          const int* __restrict__ src, const int* __restrict__ dst,
                          const float* __restrict__ dsq) {
    int t = blockIdx.x * 256 + threadIdx.x;   // E*32 threads
    int e = t >> 5, c = t & 31;
    int s = src[e], d = dst[e];
    float sc = dsq[s];
    float4 v = *(const float4*)&Xt[s * XT_COLS + prev_off + c * 4];
    float* p = &Xt[d * XT_COLS + dst_off + c * 4];
    atomicAdd(p + 0, v.x * sc);
    atomicAdd(p + 1, v.y * sc);
    atomicAdd(p + 2, v.z * sc);
    atomicAdd(p + 3, v.w * sc);
}

// X1 = -rn * (agg * dsq[n]) + X0 * (rn - 1)
__global__ void k_combine_first(float* __restrict__ Xt, const float* __restrict__ dsq,
                                const float* __restrict__ lm) {
    int t = blockIdx.x * 256 + threadIdx.x;   // N*32
    int n = t >> 5, c = t & 31;
    float rn = 2.0f / lm[0];
    float ds = dsq[n];
    float4 agg = *(const float4*)&Xt[n * XT_COLS + IN_F + c * 4];
    float4 x0  = *(const float4*)&Xt[n * XT_COLS + c * 4];
    float a = -rn * ds, b = rn - 1.0f;
    float4 r;
    r.x = a * agg.x + b * x0.x;
    r.y = a * agg.y + b * x0.y;
    r.z = a * agg.z + b * x0.z;
    r.w = a * agg.w + b * x0.w;
    *(float4*)&Xt[n * XT_COLS + IN_F + c * 4] = r;
}

// Xi = -2rn*(agg*dsq) + 2(rn-1)*Xprev - Xprevprev   (slot_off = Xi slot)
__global__ void k_combine_next(float* __restrict__ Xt, const float* __restrict__ dsq,
                               const float* __restrict__ lm, int slot_off) {
    int t = blockIdx.x * 256 + threadIdx.x;
    int n = t >> 5, c = t & 31;
    float rn = 2.0f / lm[0];
    float ds = dsq[n];
    const float* row = &Xt[n * XT_COLS];
    float4 agg = *(const float4*)&row[slot_off + c * 4];
    float4 xp  = *(const float4*)&row[slot_off - IN_F + c * 4];
    float4 xpp = *(const float4*)&row[slot_off - 2 * IN_F + c * 4];
    float a = -2.0f * rn * ds, b = 2.0f * (rn - 1.0f);
    float4 r;
    r.x = a * agg.x + b * xp.x - xpp.x;
    r.y = a * agg.y + b * xp.y - xpp.y;
    r.z = a * agg.z + b * xp.z - xpp.z;
    r.w = a * agg.w + b * xp.w - xpp.w;
    *(float4*)&Xt[n * XT_COLS + slot_off + c * 4] = r;
}

// tiny eigen-MLP: ef[64] from evals
__global__ void k_ef(const float* __restrict__ evals, const float* __restrict__ ew0,
                     const float* __restrict__ eb0, const float* __restrict__ ew1,
                     const float* __restrict__ eb1, const float* __restrict__ ew2,
                     const float* __restrict__ eb2, float* __restrict__ ef) {
    __shared__ float z0[NEIG][HDIM];
    __shared__ float sev[NEIG];
    int j = threadIdx.x;  // 0..127
    if (j < NEIG) sev[j] = evals[j];
    __syncthreads();
    float w0 = ew0[j], b0 = eb0[j];
    for (int i = 0; i < NEIG; ++i)
        z0[i][j] = fmaxf(0.0f, sev[i] * w0 + b0);
    __syncthreads();
    float z1loc[NEIG];
    float b1 = eb1[j];
    for (int i = 0; i < NEIG; ++i) {
        float s = b1;
        for (int h = 0; h < HDIM; ++h) s += z0[i][h] * ew1[h * HDIM + j];
        z1loc[i] = fmaxf(0.0f, s);
    }
    __syncthreads();
    for (int i = 0; i < NEIG; ++i) z0[i][j] = z1loc[i];
    __syncthreads();
    if (j < NEIG) {
        float s = eb2[0];
        for (int h = 0; h < HDIM; ++h) s += z0[j][h] * ew2[h];
        ef[j] = s;
    }
}

// hs_small[e,f] += sum_n evecs[n,e]*feat[n,f]  (partial outer products + atomics)
__global__ __launch_bounds__(256) void k_hs_partial(const float* __restrict__ evecs,
                                                    const float* __restrict__ feat,
                                                    float* __restrict__ hs_small) {
    __shared__ float sev[4][NEIG];
    __shared__ float sft[4][IN_F];
    float acc[32];
#pragma unroll
    for (int q = 0; q < 32; ++q) acc[q] = 0.0f;
    for (int n0 = blockIdx.x * 4; n0 < N_NODES; n0 += gridDim.x * 4) {
        int nrows = min(4, N_NODES - n0);
        for (int i = threadIdx.x; i < nrows * NEIG; i += 256)
            sev[i >> 6][i & 63] = evecs[(n0 + (i >> 6)) * NEIG + (i & 63)];
        for (int i = threadIdx.x; i < nrows * IN_F; i += 256)
            sft[i >> 7][i & 127] = feat[(n0 + (i >> 7)) * IN_F + (i & 127)];
        __syncthreads();
        for (int r = 0; r < nrows; ++r) {
#pragma unroll
            for (int q = 0; q < 32; ++q) {
                int p = threadIdx.x + 256 * q;   // e = p>>7, f = p&127
                acc[q] += sev[r][p >> 7] * sft[r][p & 127];
            }
        }
        __syncthreads();
    }
#pragma unroll
    for (int q = 0; q < 32; ++q) {
        int p = threadIdx.x + 256 * q;
        atomicAdd(&hs_small[p], acc[q]);
    }
}

// Xt[n, 512+f] = sum_e evecs[n,e] * ef[e] * hs_small[e,f]
__global__ __launch_bounds__(128) void k_hs_apply(float* __restrict__ Xt,
                                                  const float* __restrict__ evecs,
                                                  const float* __restrict__ hs_small,
                                                  const float* __restrict__ ef) {
    __shared__ float shs[NEIG * HDIM];
    __shared__ float sev[NEIG];
    int f = threadIdx.x;
    for (int i = f; i < NEIG * HDIM; i += 128) shs[i] = ef[i >> 7] * hs_small[i];
    __syncthreads();
    int n0 = blockIdx.x * 16;
    int nend = min(n0 + 16, N_NODES);
    for (int n = n0; n < nend; ++n) {
        if (f < NEIG) sev[f] = evecs[n * NEIG + f];
        __syncthreads();
        float s = 0.0f;
        for (int e = 0; e < NEIG; ++e) s += sev[e] * shs[e * HDIM + f];
        Xt[n * XT_COLS + 4 * IN_F + f] = s;
        __syncthreads();
    }
}

// out[n,f] = sum_k Xt[n,k]*W[k,f] + b[f]   (BM=64, BN=128, BK=32)
__global__ __launch_bounds__(256) void k_gemm(const float* __restrict__ Xt,
                                              const float* __restrict__ W,
                                              const float* __restrict__ bias,
                                              float* __restrict__ out) {
    __shared__ float sA[64][33];
    __shared__ float sB[32][128];
    int row0 = blockIdx.x * 64;
    int tx = threadIdx.x & 31;   // cols tx*4 .. tx*4+3
    int ty = threadIdx.x >> 5;   // rows ty*8 .. ty*8+7
    float acc[8][4];
#pragma unroll
    for (int r = 0; r < 8; ++r)
#pragma unroll
        for (int c = 0; c < 4; ++c) acc[r][c] = 0.0f;

    for (int k0 = 0; k0 < XT_COLS; k0 += 32) {
        for (int s = threadIdx.x; s < 512; s += 256) {
            int r = s >> 3, kk = (s & 7) << 2;
            int row = row0 + r; if (row >= N_NODES) row = N_NODES - 1;
            float4 v = *(const float4*)&Xt[row * XT_COLS + k0 + kk];
            sA[r][kk] = v.x; sA[r][kk + 1] = v.y; sA[r][kk + 2] = v.z; sA[r][kk + 3] = v.w;
        }
        for (int s = threadIdx.x; s < 1024; s += 256) {
            int r = s >> 5, c = (s & 31) << 2;
            *(float4*)&sB[r][c] = *(const float4*)&W[(k0 + r) * OUT_F + c];
        }
        __syncthreads();
#pragma unroll
        for (int kk = 0; kk < 32; ++kk) {
            float4 b = *(float4*)&sB[kk][tx * 4];
#pragma unroll
            for (int r = 0; r < 8; ++r) {
                float a = sA[ty * 8 + r][kk];
                acc[r][0] += a * b.x;
                acc[r][1] += a * b.y;
                acc[r][2] += a * b.z;
                acc[r][3] += a * b.w;
            }
        }
        __syncthreads();
    }
    float4 bb = *(const float4*)&bias[tx * 4];
#pragma unroll
    for (int r = 0; r < 8; ++r) {
        int row = row0 + ty * 8 + r;
        if (row < N_NODES) {
            float4 v;
            v.x = acc[r][0] + bb.x;
            v.y = acc[r][1] + bb.y;
            v.z = acc[r][2] + bb.z;
            v.w = acc[r][3] + bb.w;
            *(float4*)&out[row * OUT_F + tx * 4] = v;
        }
    }
}

__global__ void k_bn_reduce(const float* __restrict__ out, float* __restrict__ colsum,
                            float* __restrict__ colsq) {
    int f = threadIdx.x & 127, half = threadIdx.x >> 7;
    float s = 0.0f, sq = 0.0f;
    for (int n = blockIdx.x * 2 + half; n < N_NODES; n += gridDim.x * 2) {
        float v = out[n * OUT_F + f];
        s += v; sq += v * v;
    }
    __shared__ float ls[256], lq[256];
    ls[threadIdx.x] = s; lq[threadIdx.x] = sq;
    __syncthreads();
    if (half == 0) {
        atomicAdd(&colsum[f], ls[f] + ls[128 + f]);
        atomicAdd(&colsq[f], lq[f] + lq[128 + f]);
    }
}

__global__ void k_bn_apply(float* __restrict__ out, const float* __restrict__ colsum,
                           const float* __restrict__ colsq, const float* __restrict__ gamma,
                           const float* __restrict__ beta) {
    int t = blockIdx.x * 256 + threadIdx.x;   // N*32
    int n = t >> 5, c = t & 31;
    float4 v = *(float4*)&out[n * OUT_F + c * 4];
    float4 s = *(const float4*)&colsum[c * 4];
    float4 q = *(const float4*)&colsq[c * 4];
    float4 g = *(const float4*)&gamma[c * 4];
    float4 b = *(const float4*)&beta[c * 4];
    const float invN = 1.0f / (float)N_NODES;
    float mux = s.x * invN, muy = s.y * invN, muz = s.z * invN, muw = s.w * invN;
    float ix = rsqrtf(q.x * invN - mux * mux + BN_EPSF);
    float iy = rsqrtf(q.y * invN - muy * muy + BN_EPSF);
    float iz = rsqrtf(q.z * invN - muz * muz + BN_EPSF);
    float iw = rsqrtf(q.w * invN - muw * muw + BN_EPSF);
    v.x = fmaxf(0.0f, (v.x - mux) * ix * g.x + b.x);
    v.y = fmaxf(0.0f, (v.y - muy) * iy * g.y + b.y);
    v.z = fmaxf(0.0f, (v.z - muz) * iz * g.z + b.z);
    v.w = fmaxf(0.0f, (v.w - muw) * iw * g.w + b.w);
    *(float4*)&out[n * OUT_F + c * 4] = v;
}

extern "C" void kernel_launch(void* const* d_in, const int* in_sizes, int n_in,
                              void* d_out, int out_size, void* d_ws, size_t ws_size,
                              hipStream_t stream) {
    const float* feature    = (const float*)d_in[0];
    const float* lin_w      = (const float*)d_in[1];
    const float* lin_b      = (const float*)d_in[2];
    const float* ew0        = (const float*)d_in[3];
    const float* eb0        = (const float*)d_in[4];
    const float* ew1        = (const float*)d_in[5];
    const float* eb1        = (const float*)d_in[6];
    const float* ew2        = (const float*)d_in[7];
    const float* eb2        = (const float*)d_in[8];
    const float* bn_gamma   = (const float*)d_in[9];
    const float* bn_beta    = (const float*)d_in[10];
    const float* lambda_max = (const float*)d_in[11];
    const float* evecs      = (const float*)d_in[12];
    const float* evals      = (const float*)d_in[13];
    const int*   edge_src   = (const int*)d_in[14];
    const int*   edge_dst   = (const int*)d_in[15];

    float* out      = (float*)d_out;
    float* ws       = (float*)d_ws;
    float* Xt       = ws + OFF_XT;
    float* dsq      = ws + OFF_DSQRT;
    float* hs_small = ws + OFF_HS;
    float* ef       = ws + OFF_EF;
    float* colsum   = ws + OFF_COLSUM;
    float* colsq    = ws + OFF_COLSQ;

    k_zero<<<229, 256, 0, stream>>>(dsq, hs_small);
    k_init_xt<<<(N_NODES * 128) / 256, 256, 0, stream>>>(Xt, feature);
    k_deg<<<(N_EDGES + 255) / 256, 256, 0, stream>>>(dsq, edge_dst);
    k_dsqrt<<<(N_NODES + 255) / 256, 256, 0, stream>>>(dsq);

    // X1
    k_scatter<<<(N_EDGES * 32) / 256, 256, 0, stream>>>(Xt, 0, 128, edge_src, edge_dst, dsq);
    k_combine_first<<<(N_NODES * 32) / 256, 256, 0, stream>>>(Xt, dsq, lambda_max);
    // X2
    k_scatter<<<(N_EDGES * 32) / 256, 256, 0, stream>>>(Xt, 128, 256, edge_src, edge_dst, dsq);
    k_combine_next<<<(N_NODES * 32) / 256, 256, 0, stream>>>(Xt, dsq, lambda_max, 256);
    // X3
    k_scatter<<<(N_EDGES * 32) / 256, 256, 0, stream>>>(Xt, 256, 384, edge_src, edge_dst, dsq);
    k_combine_next<<<(N_NODES * 32) / 256, 256, 0, stream>>>(Xt, dsq, lambda_max, 384);

    // eigen block
    k_ef<<<1, 128, 0, stream>>>(evals, ew0, eb0, ew1, eb1, ew2, eb2, ef);
    k_hs_partial<<<256, 256, 0, stream>>>(evecs, feature, hs_small);
    k_hs_apply<<<(N_NODES + 15) / 16, 128, 0, stream>>>(Xt, evecs, hs_small, ef);

    // linear + BN + relu
    k_gemm<<<(N_NODES + 63) / 64, 256, 0, stream>>>(Xt, lin_w, lin_b, out);
    k_bn_reduce<<<256, 256, 0, stream>>>(out, colsum, colsq);
    k_bn_apply<<<(N_NODES * 32) / 256, 256, 0, stream>>>(out, colsum, colsq, bn_gamma, bn_beta);
}

// Round 2
// 1028.401 us; speedup vs baseline: 4.5506x; 4.5506x over previous
//
#include <hip/hip_runtime.h>

#define N_NODES 50000
#define N_EDGES 800000
#define IN_F    128
#define OUT_F   128
#define NEIG    64
#define HDIM    128
#define XTS_COLS 512              // stored cols 128..639; col 0..127 read from feature
#define BN_EPSF 1e-5f

// ---- workspace layout (in 4-byte units) ----
#define OFF_XTS     0                                  // 25,600,000 floats
#define OFF_DSQRT   (N_NODES * XTS_COLS)               // 25,600,000
#define OFF_HS      (OFF_DSQRT + N_NODES)              // +50,000
#define OFF_EF      (OFF_HS + NEIG * OUT_F)            // +8192
#define OFF_COLSUM  (OFF_EF + NEIG)                    // +64
#define OFF_COLSQ   (OFF_COLSUM + OUT_F)               // +128
#define OFF_DEG     (OFF_COLSQ + OUT_F)                // +128  (ints)
#define OFF_ROWSTART (OFF_DEG + N_NODES)               // +50,000 (ints, N+1)
#define OFF_CURSOR  (OFF_ROWSTART + N_NODES + 1)       // +50,001 (ints)
#define OFF_CSR     (OFF_CURSOR + N_NODES)             // +50,000 (ints, E)
// total = 26,608,513 * 4B ≈ 106.4 MB (< 128.3 MB proven in R0)

__global__ void k_zero(int* __restrict__ deg, float* __restrict__ small) {
    int i = blockIdx.x * 256 + threadIdx.x;
    if (i < N_NODES) deg[i] = 0;
    if (i < NEIG * OUT_F + NEIG + 2 * OUT_F) small[i] = 0.0f;
}

__global__ void k_deg(int* __restrict__ deg, const int* __restrict__ dst) {
    int e = blockIdx.x * 256 + threadIdx.x;
    if (e < N_EDGES) atomicAdd(&deg[dst[e]], 1);
}

// single-block exclusive scan over deg -> row_start, cursor; also dsq = rsqrt(max(deg,1))
__global__ __launch_bounds__(1024) void k_scan(const int* __restrict__ deg,
                                               int* __restrict__ row_start,
                                               int* __restrict__ cursor,
                                               float* __restrict__ dsq) {
    __shared__ int ssum[1024];
    const int CHUNK = (N_NODES + 1023) / 1024;   // 49
    int t = threadIdx.x;
    int lo = t * CHUNK, hi = min(lo + CHUNK, N_NODES);
    int s = 0;
    for (int i = lo; i < hi; ++i) s += deg[i];
    ssum[t] = s;
    __syncthreads();
    for (int off = 1; off < 1024; off <<= 1) {
        int v = (t >= off) ? ssum[t - off] : 0;
        __syncthreads();
        if (t >= off) ssum[t] += v;
        __syncthreads();
    }
    int run = ssum[t] - s;   // exclusive prefix of this thread's chunk
    for (int i = lo; i < hi; ++i) {
        int d = deg[i];
        row_start[i] = run;
        cursor[i]    = run;
        dsq[i] = rsqrtf((float)max(d, 1));
        run += d;
    }
    if (lo < N_NODES && hi == N_NODES) row_start[N_NODES] = run;
}

__global__ void k_bucket(const int* __restrict__ src, const int* __restrict__ dst,
                         int* __restrict__ cursor, int* __restrict__ csr_src) {
    int e = blockIdx.x * 256 + threadIdx.x;
    if (e < N_EDGES) {
        int d = dst[e];
        int pos = atomicAdd(&cursor[d], 1);
        csr_src[pos] = src[e];
    }
}

// One wave (64 lanes) per node, float2 per lane (128 feats).
// agg = sum_{e in in(n)} dsq[src]*srcmat[src]; out = a*dsq[n]*agg + b*prev [+ c*pp]
__global__ __launch_bounds__(256) void k_gather(const int* __restrict__ row_start,
                                                const int* __restrict__ csr_src,
                                                const float* __restrict__ dsq,
                                                const float* __restrict__ srcmat, int src_stride,
                                                const float* __restrict__ prevmat, int prev_stride,
                                                const float* __restrict__ ppmat, int pp_stride,
                                                float* __restrict__ outp,
                                                const float* __restrict__ lm, int first) {
    int n = (blockIdx.x * 256 + threadIdx.x) >> 6;
    int lane = threadIdx.x & 63;
    if (n >= N_NODES) return;
    float rn = 2.0f / lm[0];
    float ax = 0.0f, ay = 0.0f;
    int beg = row_start[n], end = row_start[n + 1];
    for (int i = beg; i < end; ++i) {
        int s = csr_src[i];
        float sc = dsq[s];
        float2 v = *(const float2*)&srcmat[s * src_stride + lane * 2];
        ax += sc * v.x;
        ay += sc * v.y;
    }
    float ds = dsq[n];
    float a = (first ? -rn : -2.0f * rn) * ds;
    float b = first ? (rn - 1.0f) : 2.0f * (rn - 1.0f);
    float2 pv = *(const float2*)&prevmat[n * prev_stride + lane * 2];
    float rx = a * ax + b * pv.x;
    float ry = a * ay + b * pv.y;
    if (ppmat) {
        float2 pp = *(const float2*)&ppmat[n * pp_stride + lane * 2];
        rx -= pp.x;
        ry -= pp.y;
    }
    *(float2*)&outp[n * XTS_COLS + lane * 2] = rx == rx ? make_float2(rx, ry) : make_float2(rx, ry);
}

// tiny eigen-MLP: ef[64] from evals
__global__ void k_ef(const float* __restrict__ evals, const float* __restrict__ ew0,
                     const float* __restrict__ eb0, const float* __restrict__ ew1,
                     const float* __restrict__ eb1, const float* __restrict__ ew2,
                     const float* __restrict__ eb2, float* __restrict__ ef) {
    __shared__ float z0[NEIG][HDIM];
    __shared__ float sev[NEIG];
    int j = threadIdx.x;  // 0..127
    if (j < NEIG) sev[j] = evals[j];
    __syncthreads();
    float w0 = ew0[j], b0 = eb0[j];
    for (int i = 0; i < NEIG; ++i)
        z0[i][j] = fmaxf(0.0f, sev[i] * w0 + b0);
    __syncthreads();
    float z1loc[NEIG];
    float b1 = eb1[j];
    for (int i = 0; i < NEIG; ++i) {
        float s = b1;
        for (int h = 0; h < HDIM; ++h) s += z0[i][h] * ew1[h * HDIM + j];
        z1loc[i] = fmaxf(0.0f, s);
    }
    __syncthreads();
    for (int i = 0; i < NEIG; ++i) z0[i][j] = z1loc[i];
    __syncthreads();
    if (j < NEIG) {
        float s = eb2[0];
        for (int h = 0; h < HDIM; ++h) s += z0[j][h] * ew2[h];
        ef[j] = s;
    }
}

// hs_small[e,f] += sum_n evecs[n,e]*feat[n,f]
__global__ __launch_bounds__(256) void k_hs_partial(const float* __restrict__ evecs,
                                                    const float* __restrict__ feat,
                                                    float* __restrict__ hs_small) {
    __shared__ float sev[4][NEIG];
    __shared__ float sft[4][IN_F];
    float acc[32];
#pragma unroll
    for (int q = 0; q < 32; ++q) acc[q] = 0.0f;
    for (int n0 = blockIdx.x * 4; n0 < N_NODES; n0 += gridDim.x * 4) {
        int nrows = min(4, N_NODES - n0);
        for (int i = threadIdx.x; i < nrows * NEIG; i += 256)
            sev[i >> 6][i & 63] = evecs[(n0 + (i >> 6)) * NEIG + (i & 63)];
        for (int i = threadIdx.x; i < nrows * IN_F; i += 256)
            sft[i >> 7][i & 127] = feat[(n0 + (i >> 7)) * IN_F + (i & 127)];
        __syncthreads();
        for (int r = 0; r < nrows; ++r) {
#pragma unroll
            for (int q = 0; q < 32; ++q) {
                int p = threadIdx.x + 256 * q;   // e = p>>7, f = p&127
                acc[q] += sev[r][p >> 7] * sft[r][p & 127];
            }
        }
        __syncthreads();
    }
#pragma unroll
    for (int q = 0; q < 32; ++q) {
        int p = threadIdx.x + 256 * q;
        atomicAdd(&hs_small[p], acc[q]);
    }
}

// XtS[n, 384+f] = sum_e evecs[n,e] * ef[e] * hs_small[e,f]
__global__ __launch_bounds__(128) void k_hs_apply(float* __restrict__ XtS,
                                                  const float* __restrict__ evecs,
                                                  const float* __restrict__ hs_small,
                                                  const float* __restrict__ ef) {
    __shared__ float shs[NEIG * HDIM];
    __shared__ float sev[NEIG];
    int f = threadIdx.x;
    for (int i = f; i < NEIG * HDIM; i += 128) shs[i] = ef[i >> 7] * hs_small[i];
    __syncthreads();
    int n0 = blockIdx.x * 16;
    int nend = min(n0 + 16, N_NODES);
    for (int n = n0; n < nend; ++n) {
        if (f < NEIG) sev[f] = evecs[n * NEIG + f];
        __syncthreads();
        float s = 0.0f;
        for (int e = 0; e < NEIG; ++e) s += sev[e] * shs[e * HDIM + f];
        XtS[n * XTS_COLS + 3 * IN_F + f] = s;
        __syncthreads();
    }
}

// out[n,f] = sum_k X[n,k]*W[k,f] + b[f]; X col 0..127 = feature, 128..639 = XtS
__global__ __launch_bounds__(256) void k_gemm(const float* __restrict__ feat,
                                              const float* __restrict__ XtS,
                                              const float* __restrict__ W,
                                              const float* __restrict__ bias,
                                              float* __restrict__ out) {
    __shared__ float sA[64][33];
    __shared__ float sB[32][128];
    int row0 = blockIdx.x * 64;
    int tx = threadIdx.x & 31;
    int ty = threadIdx.x >> 5;
    float acc[8][4];
#pragma unroll
    for (int r = 0; r < 8; ++r)
#pragma unroll
        for (int c = 0; c < 4; ++c) acc[r][c] = 0.0f;

    for (int k0 = 0; k0 < 640; k0 += 32) {
        const float* base; int stride, kk0;
        if (k0 < 128) { base = feat; stride = IN_F; kk0 = k0; }
        else          { base = XtS;  stride = XTS_COLS; kk0 = k0 - 128; }
        for (int s = threadIdx.x; s < 512; s += 256) {
            int r = s >> 3, kk = (s & 7) << 2;
            int row = row0 + r; if (row >= N_NODES) row = N_NODES - 1;
            float4 v = *(const float4*)&base[row * stride + kk0 + kk];
            sA[r][kk] = v.x; sA[r][kk + 1] = v.y; sA[r][kk + 2] = v.z; sA[r][kk + 3] = v.w;
        }
        for (int s = threadIdx.x; s < 1024; s += 256) {
            int r = s >> 5, c = (s & 31) << 2;
            *(float4*)&sB[r][c] = *(const float4*)&W[(k0 + r) * OUT_F + c];
        }
        __syncthreads();
#pragma unroll
        for (int kk = 0; kk < 32; ++kk) {
            float4 b = *(float4*)&sB[kk][tx * 4];
#pragma unroll
            for (int r = 0; r < 8; ++r) {
                float a = sA[ty * 8 + r][kk];
                acc[r][0] += a * b.x;
                acc[r][1] += a * b.y;
                acc[r][2] += a * b.z;
                acc[r][3] += a * b.w;
            }
        }
        __syncthreads();
    }
    float4 bb = *(const float4*)&bias[tx * 4];
#pragma unroll
    for (int r = 0; r < 8; ++r) {
        int row = row0 + ty * 8 + r;
        if (row < N_NODES) {
            float4 v;
            v.x = acc[r][0] + bb.x;
            v.y = acc[r][1] + bb.y;
            v.z = acc[r][2] + bb.z;
            v.w = acc[r][3] + bb.w;
            *(float4*)&out[row * OUT_F + tx * 4] = v;
        }
    }
}

__global__ void k_bn_reduce(const float* __restrict__ out, float* __restrict__ colsum,
                            float* __restrict__ colsq) {
    int f = threadIdx.x & 127, half = threadIdx.x >> 7;
    float s = 0.0f, sq = 0.0f;
    for (int n = blockIdx.x * 2 + half; n < N_NODES; n += gridDim.x * 2) {
        float v = out[n * OUT_F + f];
        s += v; sq += v * v;
    }
    __shared__ float ls[256], lq[256];
    ls[threadIdx.x] = s; lq[threadIdx.x] = sq;
    __syncthreads();
    if (half == 0) {
        atomicAdd(&colsum[f], ls[f] + ls[128 + f]);
        atomicAdd(&colsq[f], lq[f] + lq[128 + f]);
    }
}

__global__ void k_bn_apply(float* __restrict__ out, const float* __restrict__ colsum,
                           const float* __restrict__ colsq, const float* __restrict__ gamma,
                           const float* __restrict__ beta) {
    int t = blockIdx.x * 256 + threadIdx.x;
    int n = t >> 5, c = t & 31;
    float4 v = *(float4*)&out[n * OUT_F + c * 4];
    float4 s = *(const float4*)&colsum[c * 4];
    float4 q = *(const float4*)&colsq[c * 4];
    float4 g = *(const float4*)&gamma[c * 4];
    float4 b = *(const float4*)&beta[c * 4];
    const float invN = 1.0f / (float)N_NODES;
    float mux = s.x * invN, muy = s.y * invN, muz = s.z * invN, muw = s.w * invN;
    float ix = rsqrtf(q.x * invN - mux * mux + BN_EPSF);
    float iy = rsqrtf(q.y * invN - muy * muy + BN_EPSF);
    float iz = rsqrtf(q.z * invN - muz * muz + BN_EPSF);
    float iw = rsqrtf(q.w * invN - muw * muw + BN_EPSF);
    v.x = fmaxf(0.0f, (v.x - mux) * ix * g.x + b.x);
    v.y = fmaxf(0.0f, (v.y - muy) * iy * g.y + b.y);
    v.z = fmaxf(0.0f, (v.z - muz) * iz * g.z + b.z);
    v.w = fmaxf(0.0f, (v.w - muw) * iw * g.w + b.w);
    *(float4*)&out[n * OUT_F + c * 4] = v;
}

extern "C" void kernel_launch(void* const* d_in, const int* in_sizes, int n_in,
                              void* d_out, int out_size, void* d_ws, size_t ws_size,
                              hipStream_t stream) {
    const float* feature    = (const float*)d_in[0];
    const float* lin_w      = (const float*)d_in[1];
    const float* lin_b      = (const float*)d_in[2];
    const float* ew0        = (const float*)d_in[3];
    const float* eb0        = (const float*)d_in[4];
    const float* ew1        = (const float*)d_in[5];
    const float* eb1        = (const float*)d_in[6];
    const float* ew2        = (const float*)d_in[7];
    const float* eb2        = (const float*)d_in[8];
    const float* bn_gamma   = (const float*)d_in[9];
    const float* bn_beta    = (const float*)d_in[10];
    const float* lambda_max = (const float*)d_in[11];
    const float* evecs      = (const float*)d_in[12];
    const float* evals      = (const float*)d_in[13];
    const int*   edge_src   = (const int*)d_in[14];
    const int*   edge_dst   = (const int*)d_in[15];

    float* out      = (float*)d_out;
    float* ws       = (float*)d_ws;
    float* XtS      = ws + OFF_XTS;
    float* dsq      = ws + OFF_DSQRT;
    float* hs_small = ws + OFF_HS;
    float* ef       = ws + OFF_EF;
    float* colsum   = ws + OFF_COLSUM;
    float* colsq    = ws + OFF_COLSQ;
    int*   deg      = (int*)(ws + OFF_DEG);
    int*   row_start= (int*)(ws + OFF_ROWSTART);
    int*   cursor   = (int*)(ws + OFF_CURSOR);
    int*   csr_src  = (int*)(ws + OFF_CSR);

    // ---- CSR build ----
    k_zero<<<229, 256, 0, stream>>>(deg, hs_small);
    k_deg<<<(N_EDGES + 255) / 256, 256, 0, stream>>>(deg, edge_dst);
    k_scan<<<1, 1024, 0, stream>>>(deg, row_start, cursor, dsq);
    k_bucket<<<(N_EDGES + 255) / 256, 256, 0, stream>>>(edge_src, edge_dst, cursor, csr_src);

    // ---- Chebyshev recurrence (gather + fused combine) ----
    float* X1 = XtS;                 // cols 128..255
    float* X2 = XtS + IN_F;          // cols 256..383
    float* X3 = XtS + 2 * IN_F;      // cols 384..511
    const int GBLK = (N_NODES * 64 + 255) / 256;
    k_gather<<<GBLK, 256, 0, stream>>>(row_start, csr_src, dsq,
                                       feature, IN_F, feature, IN_F,
                                       (const float*)nullptr, 0,
                                       X1, lambda_max, 1);
    k_gather<<<GBLK, 256, 0, stream>>>(row_start, csr_src, dsq,
                                       X1, XTS_COLS, X1, XTS_COLS,
                                       feature, IN_F,
                                       X2, lambda_max, 0);
    k_gather<<<GBLK, 256, 0, stream>>>(row_start, csr_src, dsq,
                                       X2, XTS_COLS, X2, XTS_COLS,
                                       X1, XTS_COLS,
                                       X3, lambda_max, 0);

    // ---- eigen block ----
    k_ef<<<1, 128, 0, stream>>>(evals, ew0, eb0, ew1, eb1, ew2, eb2, ef);
    k_hs_partial<<<256, 256, 0, stream>>>(evecs, feature, hs_small);
    k_hs_apply<<<(N_NODES + 15) / 16, 128, 0, stream>>>(XtS, evecs, hs_small, ef);

    // ---- linear + BN + relu ----
    k_gemm<<<(N_NODES + 63) / 64, 256, 0, stream>>>(feature, XtS, lin_w, lin_b, out);
    k_bn_reduce<<<256, 256, 0, stream>>>(out, colsum, colsq);
    k_bn_apply<<<(N_NODES * 32) / 256, 256, 0, stream>>>(out, colsum, colsq, bn_gamma, bn_beta);
}

// Round 3
// 901.942 us; speedup vs baseline: 5.1886x; 1.1402x over previous
//
#include <hip/hip_runtime.h>

#define N_NODES 50000
#define N_EDGES 800000
#define IN_F    128
#define OUT_F   128
#define NEIG    64
#define HDIM    128
#define BN_EPSF 1e-5f
#define XB_ROWS 50048            // 50000 padded to 128
#define XB_COLS 640

typedef __attribute__((ext_vector_type(8))) short short8;
typedef __attribute__((ext_vector_type(4))) float floatx4;

// ---- workspace layout (in 4-byte units) ----
#define OFF_XB      0                                   // ushort[50048*640] -> 16,015,360 floats
#define OFF_X1F     (XB_ROWS * XB_COLS / 2)             // 16,015,360
#define OFF_X2F     (OFF_X1F + N_NODES * IN_F)          // 22,415,360
#define OFF_WT      (OFF_X2F + N_NODES * IN_F)          // 28,815,360 (ushort[640*128] = 40,960 floats)
#define OFF_DSQRT   (OFF_WT + 40960)                    // 28,856,320
#define OFF_HS      (OFF_DSQRT + N_NODES)
#define OFF_EF      (OFF_HS + NEIG * OUT_F)
#define OFF_COLSUM  (OFF_EF + NEIG)
#define OFF_COLSQ   (OFF_COLSUM + OUT_F)
#define OFF_DEG     (OFF_COLSQ + OUT_F)
#define OFF_ROWSTART (OFF_DEG + N_NODES)
#define OFF_CURSOR  (OFF_ROWSTART + N_NODES + 1)
#define OFF_CSR     (OFF_CURSOR + N_NODES)
// end ~= 29,914,801 floats ~= 119.7 MB (< 128.3 MB proven in R0)

static __device__ inline unsigned short f2bf(float f) {
    union { float f; unsigned int u; } v; v.f = f;
    unsigned int r = (v.u + 0x7FFFu + ((v.u >> 16) & 1u)) >> 16;
    return (unsigned short)r;
}
static __device__ inline float bf2f(unsigned int u16) {
    union { unsigned int u; float f; } v; v.u = u16 << 16;
    return v.f;
}

__global__ void k_zero(int* __restrict__ deg, float* __restrict__ small) {
    int i = blockIdx.x * 256 + threadIdx.x;
    if (i < N_NODES) deg[i] = 0;
    if (i < NEIG * OUT_F + NEIG + 2 * OUT_F) small[i] = 0.0f;
}

__global__ void k_deg(int* __restrict__ deg, const int* __restrict__ dst) {
    int e = blockIdx.x * 256 + threadIdx.x;
    if (e < N_EDGES) atomicAdd(&deg[dst[e]], 1);
}

// single-block exclusive scan over deg -> row_start, cursor; also dsq = rsqrt(max(deg,1))
__global__ __launch_bounds__(1024) void k_scan(const int* __restrict__ deg,
                                               int* __restrict__ row_start,
                                               int* __restrict__ cursor,
                                               float* __restrict__ dsq) {
    __shared__ int ssum[1024];
    const int CHUNK = (N_NODES + 1023) / 1024;
    int t = threadIdx.x;
    int lo = t * CHUNK, hi = min(lo + CHUNK, N_NODES);
    int s = 0;
    for (int i = lo; i < hi; ++i) s += deg[i];
    ssum[t] = s;
    __syncthreads();
    for (int off = 1; off < 1024; off <<= 1) {
        int v = (t >= off) ? ssum[t - off] : 0;
        __syncthreads();
        if (t >= off) ssum[t] += v;
        __syncthreads();
    }
    int run = ssum[t] - s;
    for (int i = lo; i < hi; ++i) {
        int d = deg[i];
        row_start[i] = run;
        cursor[i]    = run;
        dsq[i] = rsqrtf((float)max(d, 1));
        run += d;
    }
    if (lo < N_NODES && hi == N_NODES) row_start[N_NODES] = run;
}

__global__ void k_bucket(const int* __restrict__ src, const int* __restrict__ dst,
                         int* __restrict__ cursor, int* __restrict__ csr_src) {
    int e = blockIdx.x * 256 + threadIdx.x;
    if (e < N_EDGES) {
        int d = dst[e];
        int pos = atomicAdd(&cursor[d], 1);
        csr_src[pos] = src[e];
    }
}

// feature fp32 -> Xb cols 0..127 (bf16)
__global__ void k_feat2bf(const float* __restrict__ feat, unsigned short* __restrict__ Xb) {
    int t = blockIdx.x * 256 + threadIdx.x;   // N*16 threads, 8 elems each
    int n = t >> 4, c8 = (t & 15) * 8;
    float4 a = *(const float4*)&feat[n * IN_F + c8];
    float4 b = *(const float4*)&feat[n * IN_F + c8 + 4];
    ushort4 o0, o1;
    o0.x = f2bf(a.x); o0.y = f2bf(a.y); o0.z = f2bf(a.z); o0.w = f2bf(a.w);
    o1.x = f2bf(b.x); o1.y = f2bf(b.y); o1.z = f2bf(b.z); o1.w = f2bf(b.w);
    *(ushort4*)&Xb[(size_t)n * XB_COLS + c8]     = o0;
    *(ushort4*)&Xb[(size_t)n * XB_COLS + c8 + 4] = o1;
}

// W[640][128] fp32 -> Wt[128][640] bf16
__global__ void k_wt(const float* __restrict__ W, unsigned short* __restrict__ Wt) {
    int t = blockIdx.x * 256 + threadIdx.x;   // 81920
    int k = t >> 7, n = t & 127;
    Wt[n * 640 + k] = f2bf(W[k * 128 + n]);
}

// One wave per node: agg over in-edges of bf16 src rows; combine fp32; write fp32 (opt) + bf16
__global__ __launch_bounds__(256) void k_gather(const int* __restrict__ row_start,
                                                const int* __restrict__ csr_src,
                                                const float* __restrict__ dsq,
                                                const unsigned short* __restrict__ srcb, // + col off
                                                const float* __restrict__ prevmat, int prev_stride,
                                                const float* __restrict__ ppmat, int pp_stride,
                                                float* __restrict__ outf,                 // may be null
                                                unsigned short* __restrict__ outb,        // + col off
                                                const float* __restrict__ lm, int first) {
    int n = (blockIdx.x * 256 + threadIdx.x) >> 6;
    int lane = threadIdx.x & 63;
    if (n >= N_NODES) return;
    float rn = 2.0f / lm[0];
    float ax = 0.0f, ay = 0.0f;
    int beg = row_start[n], end = row_start[n + 1];
    for (int i = beg; i < end; ++i) {
        int s = csr_src[i];
        float sc = dsq[s];
        unsigned int pv = *(const unsigned int*)&srcb[(size_t)s * XB_COLS + lane * 2];
        ax += sc * bf2f(pv & 0xffffu);
        ay += sc * bf2f(pv >> 16);
    }
    float ds = dsq[n];
    float a = (first ? -rn : -2.0f * rn) * ds;
    float b = first ? (rn - 1.0f) : 2.0f * (rn - 1.0f);
    float2 pv = *(const float2*)&prevmat[(size_t)n * prev_stride + lane * 2];
    float rx = a * ax + b * pv.x;
    float ry = a * ay + b * pv.y;
    if (ppmat) {
        float2 pp = *(const float2*)&ppmat[(size_t)n * pp_stride + lane * 2];
        rx -= pp.x;
        ry -= pp.y;
    }
    if (outf) *(float2*)&outf[(size_t)n * IN_F + lane * 2] = make_float2(rx, ry);
    unsigned int packed = (unsigned int)f2bf(rx) | ((unsigned int)f2bf(ry) << 16);
    *(unsigned int*)&outb[(size_t)n * XB_COLS + lane * 2] = packed;
}

// tiny eigen-MLP: ef[64] from evals
__global__ void k_ef(const float* __restrict__ evals, const float* __restrict__ ew0,
                     const float* __restrict__ eb0, const float* __restrict__ ew1,
                     const float* __restrict__ eb1, const float* __restrict__ ew2,
                     const float* __restrict__ eb2, float* __restrict__ ef) {
    __shared__ float z0[NEIG][HDIM];
    __shared__ float sev[NEIG];
    int j = threadIdx.x;  // 0..127
    if (j < NEIG) sev[j] = evals[j];
    __syncthreads();
    float w0 = ew0[j], b0 = eb0[j];
    for (int i = 0; i < NEIG; ++i)
        z0[i][j] = fmaxf(0.0f, sev[i] * w0 + b0);
    __syncthreads();
    float z1loc[NEIG];
    float b1 = eb1[j];
    for (int i = 0; i < NEIG; ++i) {
        float s = b1;
        for (int h = 0; h < HDIM; ++h) s += z0[i][h] * ew1[h * HDIM + j];
        z1loc[i] = fmaxf(0.0f, s);
    }
    __syncthreads();
    for (int i = 0; i < NEIG; ++i) z0[i][j] = z1loc[i];
    __syncthreads();
    if (j < NEIG) {
        float s = eb2[0];
        for (int h = 0; h < HDIM; ++h) s += z0[j][h] * ew2[h];
        ef[j] = s;
    }
}

// hs_small[e,f] += sum_n evecs[n,e]*feat[n,f]
__global__ __launch_bounds__(256) void k_hs_partial(const float* __restrict__ evecs,
                                                    const float* __restrict__ feat,
                                                    float* __restrict__ hs_small) {
    __shared__ float sev[4][NEIG];
    __shared__ float sft[4][IN_F];
    float acc[32];
#pragma unroll
    for (int q = 0; q < 32; ++q) acc[q] = 0.0f;
    for (int n0 = blockIdx.x * 4; n0 < N_NODES; n0 += gridDim.x * 4) {
        int nrows = min(4, N_NODES - n0);
        for (int i = threadIdx.x; i < nrows * NEIG; i += 256)
            sev[i >> 6][i & 63] = evecs[(n0 + (i >> 6)) * NEIG + (i & 63)];
        for (int i = threadIdx.x; i < nrows * IN_F; i += 256)
            sft[i >> 7][i & 127] = feat[(n0 + (i >> 7)) * IN_F + (i & 127)];
        __syncthreads();
        for (int r = 0; r < nrows; ++r) {
#pragma unroll
            for (int q = 0; q < 32; ++q) {
                int p = threadIdx.x + 256 * q;   // e = p>>7, f = p&127
                acc[q] += sev[r][p >> 7] * sft[r][p & 127];
            }
        }
        __syncthreads();
    }
#pragma unroll
    for (int q = 0; q < 32; ++q) {
        int p = threadIdx.x + 256 * q;
        atomicAdd(&hs_small[p], acc[q]);
    }
}

// Xb[n, 512+f] = bf16( sum_e evecs[n,e] * ef[e] * hs_small[e,f] )
__global__ __launch_bounds__(128) void k_hs_apply(unsigned short* __restrict__ Xb,
                                                  const float* __restrict__ evecs,
                                                  const float* __restrict__ hs_small,
                                                  const float* __restrict__ ef) {
    __shared__ float shs[NEIG * HDIM];
    __shared__ float sev[NEIG];
    int f = threadIdx.x;
    for (int i = f; i < NEIG * HDIM; i += 128) shs[i] = ef[i >> 7] * hs_small[i];
    __syncthreads();
    int n0 = blockIdx.x * 16;
    int nend = min(n0 + 16, N_NODES);
    for (int n = n0; n < nend; ++n) {
        if (f < NEIG) sev[f] = evecs[n * NEIG + f];
        __syncthreads();
        float s = 0.0f;
        for (int e = 0; e < NEIG; ++e) s += sev[e] * shs[e * HDIM + f];
        Xb[(size_t)n * XB_COLS + 4 * IN_F + f] = f2bf(s);
        __syncthreads();
    }
}

// MFMA bf16 GEMM: out[m,n] = Xb[m,:] @ W[:,n] + bias[n]; A=Xb row-major, B=Wt (n-major)
__global__ __launch_bounds__(256) void k_gemm(const unsigned short* __restrict__ Xb,
                                              const unsigned short* __restrict__ Wt,
                                              const float* __restrict__ bias,
                                              float* __restrict__ out) {
    __shared__ unsigned short sA[128 * 32];  // [r][k]
    __shared__ unsigned short sB[128 * 32];  // [n][k]
    int tid = threadIdx.x;
    int wave = tid >> 6, lane = tid & 63;
    int quad = lane >> 4, m16 = lane & 15;
    int row0 = blockIdx.x * 128;

    floatx4 acc[2][8];
#pragma unroll
    for (int mt = 0; mt < 2; ++mt)
#pragma unroll
        for (int nt = 0; nt < 8; ++nt) acc[mt][nt] = (floatx4)(0.0f);

    int r  = tid >> 2;          // 0..63
    int c8 = (tid & 3) * 8;     // 0,8,16,24
    int gr0 = min(row0 + r, N_NODES - 1);
    int gr1 = min(row0 + r + 64, N_NODES - 1);

    for (int k0 = 0; k0 < 640; k0 += 32) {
        *(uint4*)&sA[r * 32 + c8]        = *(const uint4*)&Xb[(size_t)gr0 * XB_COLS + k0 + c8];
        *(uint4*)&sA[(r + 64) * 32 + c8] = *(const uint4*)&Xb[(size_t)gr1 * XB_COLS + k0 + c8];
        *(uint4*)&sB[r * 32 + c8]        = *(const uint4*)&Wt[r * 640 + k0 + c8];
        *(uint4*)&sB[(r + 64) * 32 + c8] = *(const uint4*)&Wt[(r + 64) * 640 + k0 + c8];
        __syncthreads();
        short8 a0 = *(short8*)&sA[(wave * 32 + m16) * 32 + quad * 8];
        short8 a1 = *(short8*)&sA[(wave * 32 + 16 + m16) * 32 + quad * 8];
#pragma unroll
        for (int nt = 0; nt < 8; ++nt) {
            short8 b = *(short8*)&sB[(nt * 16 + m16) * 32 + quad * 8];
            acc[0][nt] = __builtin_amdgcn_mfma_f32_16x16x32_bf16(a0, b, acc[0][nt], 0, 0, 0);
            acc[1][nt] = __builtin_amdgcn_mfma_f32_16x16x32_bf16(a1, b, acc[1][nt], 0, 0, 0);
        }
        __syncthreads();
    }
    // C/D: col = lane&15 (within 16-tile), row = quad*4 + reg
#pragma unroll
    for (int mt = 0; mt < 2; ++mt) {
        int rbase = row0 + wave * 32 + mt * 16 + quad * 4;
#pragma unroll
        for (int nt = 0; nt < 8; ++nt) {
            int col = nt * 16 + m16;
            float bb = bias[col];
#pragma unroll
            for (int reg = 0; reg < 4; ++reg) {
                int row = rbase + reg;
                if (row < N_NODES) out[(size_t)row * OUT_F + col] = acc[mt][nt][reg] + bb;
            }
        }
    }
}

__global__ void k_bn_reduce(const float* __restrict__ out, float* __restrict__ colsum,
                            float* __restrict__ colsq) {
    int f = threadIdx.x & 127, half = threadIdx.x >> 7;
    float s = 0.0f, sq = 0.0f;
    for (int n = blockIdx.x * 2 + half; n < N_NODES; n += gridDim.x * 2) {
        float v = out[n * OUT_F + f];
        s += v; sq += v * v;
    }
    __shared__ float ls[256], lq[256];
    ls[threadIdx.x] = s; lq[threadIdx.x] = sq;
    __syncthreads();
    if (half == 0) {
        atomicAdd(&colsum[f], ls[f] + ls[128 + f]);
        atomicAdd(&colsq[f], lq[f] + lq[128 + f]);
    }
}

__global__ void k_bn_apply(float* __restrict__ out, const float* __restrict__ colsum,
                           const float* __restrict__ colsq, const float* __restrict__ gamma,
                           const float* __restrict__ beta) {
    int t = blockIdx.x * 256 + threadIdx.x;
    int n = t >> 5, c = t & 31;
    float4 v = *(float4*)&out[n * OUT_F + c * 4];
    float4 s = *(const float4*)&colsum[c * 4];
    float4 q = *(const float4*)&colsq[c * 4];
    float4 g = *(const float4*)&gamma[c * 4];
    float4 b = *(const float4*)&beta[c * 4];
    const float invN = 1.0f / (float)N_NODES;
    float mux = s.x * invN, muy = s.y * invN, muz = s.z * invN, muw = s.w * invN;
    float ix = rsqrtf(q.x * invN - mux * mux + BN_EPSF);
    float iy = rsqrtf(q.y * invN - muy * muy + BN_EPSF);
    float iz = rsqrtf(q.z * invN - muz * muz + BN_EPSF);
    float iw = rsqrtf(q.w * invN - muw * muw + BN_EPSF);
    v.x = fmaxf(0.0f, (v.x - mux) * ix * g.x + b.x);
    v.y = fmaxf(0.0f, (v.y - muy) * iy * g.y + b.y);
    v.z = fmaxf(0.0f, (v.z - muz) * iz * g.z + b.z);
    v.w = fmaxf(0.0f, (v.w - muw) * iw * g.w + b.w);
    *(float4*)&out[n * OUT_F + c * 4] = v;
}

extern "C" void kernel_launch(void* const* d_in, const int* in_sizes, int n_in,
                              void* d_out, int out_size, void* d_ws, size_t ws_size,
                              hipStream_t stream) {
    const float* feature    = (const float*)d_in[0];
    const float* lin_w      = (const float*)d_in[1];
    const float* lin_b      = (const float*)d_in[2];
    const float* ew0        = (const float*)d_in[3];
    const float* eb0        = (const float*)d_in[4];
    const float* ew1        = (const float*)d_in[5];
    const float* eb1        = (const float*)d_in[6];
    const float* ew2        = (const float*)d_in[7];
    const float* eb2        = (const float*)d_in[8];
    const float* bn_gamma   = (const float*)d_in[9];
    const float* bn_beta    = (const float*)d_in[10];
    const float* lambda_max = (const float*)d_in[11];
    const float* evecs      = (const float*)d_in[12];
    const float* evals      = (const float*)d_in[13];
    const int*   edge_src   = (const int*)d_in[14];
    const int*   edge_dst   = (const int*)d_in[15];

    float* out = (float*)d_out;
    float* ws  = (float*)d_ws;
    unsigned short* Xb = (unsigned short*)(ws + OFF_XB);
    float* X1f      = ws + OFF_X1F;
    float* X2f      = ws + OFF_X2F;
    unsigned short* Wt = (unsigned short*)(ws + OFF_WT);
    float* dsq      = ws + OFF_DSQRT;
    float* hs_small = ws + OFF_HS;
    float* ef       = ws + OFF_EF;
    float* colsum   = ws + OFF_COLSUM;
    float* colsq    = ws + OFF_COLSQ;
    int*   deg      = (int*)(ws + OFF_DEG);
    int*   row_start= (int*)(ws + OFF_ROWSTART);
    int*   cursor   = (int*)(ws + OFF_CURSOR);
    int*   csr_src  = (int*)(ws + OFF_CSR);

    // ---- CSR build + conversions ----
    k_zero<<<229, 256, 0, stream>>>(deg, hs_small);
    k_deg<<<(N_EDGES + 255) / 256, 256, 0, stream>>>(deg, edge_dst);
    k_feat2bf<<<(N_NODES * 16 + 255) / 256, 256, 0, stream>>>(feature, Xb);
    k_wt<<<320, 256, 0, stream>>>(lin_w, Wt);
    k_scan<<<1, 1024, 0, stream>>>(deg, row_start, cursor, dsq);
    k_bucket<<<(N_EDGES + 255) / 256, 256, 0, stream>>>(edge_src, edge_dst, cursor, csr_src);

    // ---- Chebyshev recurrence ----
    const int GBLK = (N_NODES * 64 + 255) / 256;
    // X1 : src = Xb cols 0..127 (feat bf16); prev = feature fp32; out fp32 X1f + Xb cols 128..255
    k_gather<<<GBLK, 256, 0, stream>>>(row_start, csr_src, dsq,
                                       Xb + 0, feature, IN_F,
                                       (const float*)nullptr, 0,
                                       X1f, Xb + IN_F, lambda_max, 1);
    // X2 : src = Xb cols 128..255; prev = X1f; pp = feature; out X2f + Xb cols 256..383
    k_gather<<<GBLK, 256, 0, stream>>>(row_start, csr_src, dsq,
                                       Xb + IN_F, X1f, IN_F,
                                       feature, IN_F,
                                       X2f, Xb + 2 * IN_F, lambda_max, 0);
    // X3 : src = Xb cols 256..383; prev = X2f; pp = X1f; out bf16 only, Xb cols 384..511
    k_gather<<<GBLK, 256, 0, stream>>>(row_start, csr_src, dsq,
                                       Xb + 2 * IN_F, X2f, IN_F,
                                       X1f, IN_F,
                                       (float*)nullptr, Xb + 3 * IN_F, lambda_max, 0);

    // ---- eigen block ----
    k_ef<<<1, 128, 0, stream>>>(evals, ew0, eb0, ew1, eb1, ew2, eb2, ef);
    k_hs_partial<<<256, 256, 0, stream>>>(evecs, feature, hs_small);
    k_hs_apply<<<(N_NODES + 15) / 16, 128, 0, stream>>>(Xb, evecs, hs_small, ef);

    // ---- MFMA linear + BN + relu ----
    k_gemm<<<(N_NODES + 127) / 128, 256, 0, stream>>>(Xb, Wt, lin_b, out);
    k_bn_reduce<<<256, 256, 0, stream>>>(out, colsum, colsq);
    k_bn_apply<<<(N_NODES * 32) / 256, 256, 0, stream>>>(out, colsum, colsq, bn_gamma, bn_beta);
}

// Round 4
// 655.113 us; speedup vs baseline: 7.1435x; 1.3768x over previous
//
#include <hip/hip_runtime.h>

#define N_NODES 50000
#define N_EDGES 800000
#define IN_F    128
#define OUT_F   128
#define NEIG    64
#define HDIM    128
#define BN_EPSF 1e-5f
#define XB_ROWS 50048            // 50000 padded to 128
#define XB_COLS 640
#define SCAN_BLK 49              // ceil(50000/1024)

typedef __attribute__((ext_vector_type(8))) short short8;
typedef __attribute__((ext_vector_type(4))) float floatx4;

// ---- workspace layout (in 4-byte units) ----
#define OFF_XB      0                                   // ushort[50048*640] -> 16,015,360 floats
#define OFF_X1F     (XB_ROWS * XB_COLS / 2)             // 16,015,360
#define OFF_X2F     (OFF_X1F + N_NODES * IN_F)          // 22,415,360
#define OFF_WT      (OFF_X2F + N_NODES * IN_F)          // 28,815,360 (ushort[640*128] = 40,960 floats)
#define OFF_DSQRT   (OFF_WT + 40960)                    // 28,856,320
#define OFF_HS      (OFF_DSQRT + N_NODES)
#define OFF_EF      (OFF_HS + NEIG * OUT_F)
#define OFF_COLSUM  (OFF_EF + NEIG)
#define OFF_COLSQ   (OFF_COLSUM + OUT_F)
#define OFF_DEG     (OFF_COLSQ + OUT_F)
#define OFF_ROWSTART (OFF_DEG + N_NODES)
#define OFF_CURSOR  (OFF_ROWSTART + N_NODES + 1)
#define OFF_CSR     (OFF_CURSOR + N_NODES)
#define OFF_BSUM    (OFF_CSR + N_EDGES)                 // 64 ints
// end ~= 29,914,865 floats ~= 119.7 MB (< 128.3 MB proven in R0)

static __device__ inline unsigned short f2bf(float f) {
    union { float f; unsigned int u; } v; v.f = f;
    unsigned int r = (v.u + 0x7FFFu + ((v.u >> 16) & 1u)) >> 16;
    return (unsigned short)r;
}
static __device__ inline float bf2f(unsigned int u16) {
    union { unsigned int u; float f; } v; v.u = u16 << 16;
    return v.f;
}

__global__ void k_zero(int* __restrict__ deg, float* __restrict__ small) {
    int i = blockIdx.x * 256 + threadIdx.x;
    if (i < N_NODES) deg[i] = 0;
    if (i < NEIG * OUT_F + NEIG + 2 * OUT_F) small[i] = 0.0f;
}

__global__ void k_deg(int* __restrict__ deg, const int* __restrict__ dst) {
    int e = blockIdx.x * 256 + threadIdx.x;
    if (e < N_EDGES) atomicAdd(&deg[dst[e]], 1);
}

// ---- 3-stage parallel scan ----
// stage 1: per-block exclusive scan of deg -> row_start (local), block total -> bsum
__global__ __launch_bounds__(1024) void k_scan1(const int* __restrict__ deg,
                                                int* __restrict__ row_start,
                                                int* __restrict__ bsum) {
    __shared__ int sd[1024];
    int i = blockIdx.x * 1024 + threadIdx.x;
    int v = (i < N_NODES) ? deg[i] : 0;
    sd[threadIdx.x] = v;
    __syncthreads();
    for (int off = 1; off < 1024; off <<= 1) {
        int t = (threadIdx.x >= off) ? sd[threadIdx.x - off] : 0;
        __syncthreads();
        sd[threadIdx.x] += t;
        __syncthreads();
    }
    if (i < N_NODES) row_start[i] = sd[threadIdx.x] - v;   // local exclusive
    if (threadIdx.x == 1023) bsum[blockIdx.x] = sd[1023];
}

// stage 2: one wave scans the block sums -> exclusive offsets in place
__global__ void k_scan2(int* __restrict__ bsum) {
    int t = threadIdx.x;   // 64 threads
    int orig = (t < SCAN_BLK) ? bsum[t] : 0;
    int v = orig;
    for (int off = 1; off < 64; off <<= 1) {
        int u = __shfl_up(v, off);
        if (t >= off) v += u;
    }
    if (t < SCAN_BLK) bsum[t] = v - orig;   // exclusive
}

// stage 3: add block offset; init cursor, dsq, row_start[N]
__global__ __launch_bounds__(1024) void k_scan3(const int* __restrict__ deg,
                                                int* __restrict__ row_start,
                                                const int* __restrict__ bsum,
                                                int* __restrict__ cursor,
                                                float* __restrict__ dsq) {
    int i = blockIdx.x * 1024 + threadIdx.x;
    if (i < N_NODES) {
        int r = row_start[i] + bsum[blockIdx.x];
        row_start[i] = r;
        cursor[i] = r;
        dsq[i] = rsqrtf((float)max(deg[i], 1));
    }
    if (i == 0) row_start[N_NODES] = N_EDGES;
}

__global__ void k_bucket(const int* __restrict__ src, const int* __restrict__ dst,
                         int* __restrict__ cursor, int* __restrict__ csr_src) {
    int e = blockIdx.x * 256 + threadIdx.x;
    if (e < N_EDGES) {
        int d = dst[e];
        int pos = atomicAdd(&cursor[d], 1);
        csr_src[pos] = src[e];
    }
}

// feature fp32 -> Xb cols 0..127 (bf16)
__global__ void k_feat2bf(const float* __restrict__ feat, unsigned short* __restrict__ Xb) {
    int t = blockIdx.x * 256 + threadIdx.x;
    int n = t >> 4, c8 = (t & 15) * 8;
    float4 a = *(const float4*)&feat[n * IN_F + c8];
    float4 b = *(const float4*)&feat[n * IN_F + c8 + 4];
    ushort4 o0, o1;
    o0.x = f2bf(a.x); o0.y = f2bf(a.y); o0.z = f2bf(a.z); o0.w = f2bf(a.w);
    o1.x = f2bf(b.x); o1.y = f2bf(b.y); o1.z = f2bf(b.z); o1.w = f2bf(b.w);
    *(ushort4*)&Xb[(size_t)n * XB_COLS + c8]     = o0;
    *(ushort4*)&Xb[(size_t)n * XB_COLS + c8 + 4] = o1;
}

// W[640][128] fp32 -> Wt[128][640] bf16
__global__ void k_wt(const float* __restrict__ W, unsigned short* __restrict__ Wt) {
    int t = blockIdx.x * 256 + threadIdx.x;
    int k = t >> 7, n = t & 127;
    Wt[n * 640 + k] = f2bf(W[k * 128 + n]);
}

// One wave per node; 4x unrolled edge loop to keep 4 row-fetches in flight.
__global__ __launch_bounds__(256) void k_gather(const int* __restrict__ row_start,
                                                const int* __restrict__ csr_src,
                                                const float* __restrict__ dsq,
                                                const unsigned short* __restrict__ srcb,
                                                const float* __restrict__ prevmat, int prev_stride,
                                                const float* __restrict__ ppmat, int pp_stride,
                                                float* __restrict__ outf,
                                                unsigned short* __restrict__ outb,
                                                const float* __restrict__ lm, int first) {
    int n = (blockIdx.x * 256 + threadIdx.x) >> 6;
    int lane = threadIdx.x & 63;
    if (n >= N_NODES) return;
    float rn = 2.0f / lm[0];
    float ax = 0.0f, ay = 0.0f;
    int beg = row_start[n], end = row_start[n + 1];
    int i = beg;
    for (; i + 4 <= end; i += 4) {
        int s0 = __builtin_amdgcn_readfirstlane(csr_src[i]);
        int s1 = __builtin_amdgcn_readfirstlane(csr_src[i + 1]);
        int s2 = __builtin_amdgcn_readfirstlane(csr_src[i + 2]);
        int s3 = __builtin_amdgcn_readfirstlane(csr_src[i + 3]);
        float c0 = dsq[s0], c1 = dsq[s1], c2 = dsq[s2], c3 = dsq[s3];
        unsigned int p0 = *(const unsigned int*)&srcb[(size_t)s0 * XB_COLS + lane * 2];
        unsigned int p1 = *(const unsigned int*)&srcb[(size_t)s1 * XB_COLS + lane * 2];
        unsigned int p2 = *(const unsigned int*)&srcb[(size_t)s2 * XB_COLS + lane * 2];
        unsigned int p3 = *(const unsigned int*)&srcb[(size_t)s3 * XB_COLS + lane * 2];
        ax += c0 * bf2f(p0 & 0xffffu) + c1 * bf2f(p1 & 0xffffu)
            + c2 * bf2f(p2 & 0xffffu) + c3 * bf2f(p3 & 0xffffu);
        ay += c0 * bf2f(p0 >> 16) + c1 * bf2f(p1 >> 16)
            + c2 * bf2f(p2 >> 16) + c3 * bf2f(p3 >> 16);
    }
    for (; i < end; ++i) {
        int s = __builtin_amdgcn_readfirstlane(csr_src[i]);
        float sc = dsq[s];
        unsigned int pv = *(const unsigned int*)&srcb[(size_t)s * XB_COLS + lane * 2];
        ax += sc * bf2f(pv & 0xffffu);
        ay += sc * bf2f(pv >> 16);
    }
    float ds = dsq[n];
    float a = (first ? -rn : -2.0f * rn) * ds;
    float b = first ? (rn - 1.0f) : 2.0f * (rn - 1.0f);
    float2 pv = *(const float2*)&prevmat[(size_t)n * prev_stride + lane * 2];
    float rx = a * ax + b * pv.x;
    float ry = a * ay + b * pv.y;
    if (ppmat) {
        float2 pp = *(const float2*)&ppmat[(size_t)n * pp_stride + lane * 2];
        rx -= pp.x;
        ry -= pp.y;
    }
    if (outf) *(float2*)&outf[(size_t)n * IN_F + lane * 2] = make_float2(rx, ry);
    unsigned int packed = (unsigned int)f2bf(rx) | ((unsigned int)f2bf(ry) << 16);
    *(unsigned int*)&outb[(size_t)n * XB_COLS + lane * 2] = packed;
}

// tiny eigen-MLP: ef[64] from evals
__global__ void k_ef(const float* __restrict__ evals, const float* __restrict__ ew0,
                     const float* __restrict__ eb0, const float* __restrict__ ew1,
                     const float* __restrict__ eb1, const float* __restrict__ ew2,
                     const float* __restrict__ eb2, float* __restrict__ ef) {
    __shared__ float z0[NEIG][HDIM];
    __shared__ float sev[NEIG];
    int j = threadIdx.x;  // 0..127
    if (j < NEIG) sev[j] = evals[j];
    __syncthreads();
    float w0 = ew0[j], b0 = eb0[j];
    for (int i = 0; i < NEIG; ++i)
        z0[i][j] = fmaxf(0.0f, sev[i] * w0 + b0);
    __syncthreads();
    float z1loc[NEIG];
    float b1 = eb1[j];
    for (int i = 0; i < NEIG; ++i) {
        float s = b1;
        for (int h = 0; h < HDIM; ++h) s += z0[i][h] * ew1[h * HDIM + j];
        z1loc[i] = fmaxf(0.0f, s);
    }
    __syncthreads();
    for (int i = 0; i < NEIG; ++i) z0[i][j] = z1loc[i];
    __syncthreads();
    if (j < NEIG) {
        float s = eb2[0];
        for (int h = 0; h < HDIM; ++h) s += z0[j][h] * ew2[h];
        ef[j] = s;
    }
}

// hs_small[e,f] += sum_n evecs[n,e]*feat[n,f]
__global__ __launch_bounds__(256) void k_hs_partial(const float* __restrict__ evecs,
                                                    const float* __restrict__ feat,
                                                    float* __restrict__ hs_small) {
    __shared__ float sev[4][NEIG];
    __shared__ float sft[4][IN_F];
    float acc[32];
#pragma unroll
    for (int q = 0; q < 32; ++q) acc[q] = 0.0f;
    for (int n0 = blockIdx.x * 4; n0 < N_NODES; n0 += gridDim.x * 4) {
        int nrows = min(4, N_NODES - n0);
        for (int i = threadIdx.x; i < nrows * NEIG; i += 256)
            sev[i >> 6][i & 63] = evecs[(n0 + (i >> 6)) * NEIG + (i & 63)];
        for (int i = threadIdx.x; i < nrows * IN_F; i += 256)
            sft[i >> 7][i & 127] = feat[(n0 + (i >> 7)) * IN_F + (i & 127)];
        __syncthreads();
        for (int r = 0; r < nrows; ++r) {
#pragma unroll
            for (int q = 0; q < 32; ++q) {
                int p = threadIdx.x + 256 * q;
                acc[q] += sev[r][p >> 7] * sft[r][p & 127];
            }
        }
        __syncthreads();
    }
#pragma unroll
    for (int q = 0; q < 32; ++q) {
        int p = threadIdx.x + 256 * q;
        atomicAdd(&hs_small[p], acc[q]);
    }
}

// Xb[n, 512+f] = bf16( sum_e evecs[n,e] * ef[e] * hs_small[e,f] )
__global__ __launch_bounds__(128) void k_hs_apply(unsigned short* __restrict__ Xb,
                                                  const float* __restrict__ evecs,
                                                  const float* __restrict__ hs_small,
                                                  const float* __restrict__ ef) {
    __shared__ float shs[NEIG * HDIM];
    __shared__ float sev[NEIG];
    int f = threadIdx.x;
    for (int i = f; i < NEIG * HDIM; i += 128) shs[i] = ef[i >> 7] * hs_small[i];
    __syncthreads();
    int n0 = blockIdx.x * 16;
    int nend = min(n0 + 16, N_NODES);
    for (int n = n0; n < nend; ++n) {
        if (f < NEIG) sev[f] = evecs[n * NEIG + f];
        __syncthreads();
        float s = 0.0f;
        for (int e = 0; e < NEIG; ++e) s += sev[e] * shs[e * HDIM + f];
        Xb[(size_t)n * XB_COLS + 4 * IN_F + f] = f2bf(s);
        __syncthreads();
    }
}

// MFMA bf16 GEMM
__global__ __launch_bounds__(256) void k_gemm(const unsigned short* __restrict__ Xb,
                                              const unsigned short* __restrict__ Wt,
                                              const float* __restrict__ bias,
                                              float* __restrict__ out) {
    __shared__ unsigned short sA[128 * 32];
    __shared__ unsigned short sB[128 * 32];
    int tid = threadIdx.x;
    int wave = tid >> 6, lane = tid & 63;
    int quad = lane >> 4, m16 = lane & 15;
    int row0 = blockIdx.x * 128;

    floatx4 acc[2][8];
#pragma unroll
    for (int mt = 0; mt < 2; ++mt)
#pragma unroll
        for (int nt = 0; nt < 8; ++nt) acc[mt][nt] = (floatx4)(0.0f);

    int r  = tid >> 2;
    int c8 = (tid & 3) * 8;
    int gr0 = min(row0 + r, N_NODES - 1);
    int gr1 = min(row0 + r + 64, N_NODES - 1);

    for (int k0 = 0; k0 < 640; k0 += 32) {
        *(uint4*)&sA[r * 32 + c8]        = *(const uint4*)&Xb[(size_t)gr0 * XB_COLS + k0 + c8];
        *(uint4*)&sA[(r + 64) * 32 + c8] = *(const uint4*)&Xb[(size_t)gr1 * XB_COLS + k0 + c8];
        *(uint4*)&sB[r * 32 + c8]        = *(const uint4*)&Wt[r * 640 + k0 + c8];
        *(uint4*)&sB[(r + 64) * 32 + c8] = *(const uint4*)&Wt[(r + 64) * 640 + k0 + c8];
        __syncthreads();
        short8 a0 = *(short8*)&sA[(wave * 32 + m16) * 32 + quad * 8];
        short8 a1 = *(short8*)&sA[(wave * 32 + 16 + m16) * 32 + quad * 8];
#pragma unroll
        for (int nt = 0; nt < 8; ++nt) {
            short8 b = *(short8*)&sB[(nt * 16 + m16) * 32 + quad * 8];
            acc[0][nt] = __builtin_amdgcn_mfma_f32_16x16x32_bf16(a0, b, acc[0][nt], 0, 0, 0);
            acc[1][nt] = __builtin_amdgcn_mfma_f32_16x16x32_bf16(a1, b, acc[1][nt], 0, 0, 0);
        }
        __syncthreads();
    }
#pragma unroll
    for (int mt = 0; mt < 2; ++mt) {
        int rbase = row0 + wave * 32 + mt * 16 + quad * 4;
#pragma unroll
        for (int nt = 0; nt < 8; ++nt) {
            int col = nt * 16 + m16;
            float bb = bias[col];
#pragma unroll
            for (int reg = 0; reg < 4; ++reg) {
                int row = rbase + reg;
                if (row < N_NODES) out[(size_t)row * OUT_F + col] = acc[mt][nt][reg] + bb;
            }
        }
    }
}

__global__ void k_bn_reduce(const float* __restrict__ out, float* __restrict__ colsum,
                            float* __restrict__ colsq) {
    int f = threadIdx.x & 127, half = threadIdx.x >> 7;
    float s = 0.0f, sq = 0.0f;
    for (int n = blockIdx.x * 2 + half; n < N_NODES; n += gridDim.x * 2) {
        float v = out[n * OUT_F + f];
        s += v; sq += v * v;
    }
    __shared__ float ls[256], lq[256];
    ls[threadIdx.x] = s; lq[threadIdx.x] = sq;
    __syncthreads();
    if (half == 0) {
        atomicAdd(&colsum[f], ls[f] + ls[128 + f]);
        atomicAdd(&colsq[f], lq[f] + lq[128 + f]);
    }
}

__global__ void k_bn_apply(float* __restrict__ out, const float* __restrict__ colsum,
                           const float* __restrict__ colsq, const float* __restrict__ gamma,
                           const float* __restrict__ beta) {
    int t = blockIdx.x * 256 + threadIdx.x;
    int n = t >> 5, c = t & 31;
    float4 v = *(float4*)&out[n * OUT_F + c * 4];
    float4 s = *(const float4*)&colsum[c * 4];
    float4 q = *(const float4*)&colsq[c * 4];
    float4 g = *(const float4*)&gamma[c * 4];
    float4 b = *(const float4*)&beta[c * 4];
    const float invN = 1.0f / (float)N_NODES;
    float mux = s.x * invN, muy = s.y * invN, muz = s.z * invN, muw = s.w * invN;
    float ix = rsqrtf(q.x * invN - mux * mux + BN_EPSF);
    float iy = rsqrtf(q.y * invN - muy * muy + BN_EPSF);
    float iz = rsqrtf(q.z * invN - muz * muz + BN_EPSF);
    float iw = rsqrtf(q.w * invN - muw * muw + BN_EPSF);
    v.x = fmaxf(0.0f, (v.x - mux) * ix * g.x + b.x);
    v.y = fmaxf(0.0f, (v.y - muy) * iy * g.y + b.y);
    v.z = fmaxf(0.0f, (v.z - muz) * iz * g.z + b.z);
    v.w = fmaxf(0.0f, (v.w - muw) * iw * g.w + b.w);
    *(float4*)&out[n * OUT_F + c * 4] = v;
}

extern "C" void kernel_launch(void* const* d_in, const int* in_sizes, int n_in,
                              void* d_out, int out_size, void* d_ws, size_t ws_size,
                              hipStream_t stream) {
    const float* feature    = (const float*)d_in[0];
    const float* lin_w      = (const float*)d_in[1];
    const float* lin_b      = (const float*)d_in[2];
    const float* ew0        = (const float*)d_in[3];
    const float* eb0        = (const float*)d_in[4];
    const float* ew1        = (const float*)d_in[5];
    const float* eb1        = (const float*)d_in[6];
    const float* ew2        = (const float*)d_in[7];
    const float* eb2        = (const float*)d_in[8];
    const float* bn_gamma   = (const float*)d_in[9];
    const float* bn_beta    = (const float*)d_in[10];
    const float* lambda_max = (const float*)d_in[11];
    const float* evecs      = (const float*)d_in[12];
    const float* evals      = (const float*)d_in[13];
    const int*   edge_src   = (const int*)d_in[14];
    const int*   edge_dst   = (const int*)d_in[15];

    float* out = (float*)d_out;
    float* ws  = (float*)d_ws;
    unsigned short* Xb = (unsigned short*)(ws + OFF_XB);
    float* X1f      = ws + OFF_X1F;
    float* X2f      = ws + OFF_X2F;
    unsigned short* Wt = (unsigned short*)(ws + OFF_WT);
    float* dsq      = ws + OFF_DSQRT;
    float* hs_small = ws + OFF_HS;
    float* ef       = ws + OFF_EF;
    float* colsum   = ws + OFF_COLSUM;
    float* colsq    = ws + OFF_COLSQ;
    int*   deg      = (int*)(ws + OFF_DEG);
    int*   row_start= (int*)(ws + OFF_ROWSTART);
    int*   cursor   = (int*)(ws + OFF_CURSOR);
    int*   csr_src  = (int*)(ws + OFF_CSR);
    int*   bsum     = (int*)(ws + OFF_BSUM);

    // ---- CSR build + conversions ----
    k_zero<<<229, 256, 0, stream>>>(deg, hs_small);
    k_deg<<<(N_EDGES + 255) / 256, 256, 0, stream>>>(deg, edge_dst);
    k_feat2bf<<<(N_NODES * 16 + 255) / 256, 256, 0, stream>>>(feature, Xb);
    k_wt<<<320, 256, 0, stream>>>(lin_w, Wt);
    k_scan1<<<SCAN_BLK, 1024, 0, stream>>>(deg, row_start, bsum);
    k_scan2<<<1, 64, 0, stream>>>(bsum);
    k_scan3<<<SCAN_BLK, 1024, 0, stream>>>(deg, row_start, bsum, cursor, dsq);
    k_bucket<<<(N_EDGES + 255) / 256, 256, 0, stream>>>(edge_src, edge_dst, cursor, csr_src);

    // ---- Chebyshev recurrence ----
    const int GBLK = (N_NODES * 64 + 255) / 256;
    k_gather<<<GBLK, 256, 0, stream>>>(row_start, csr_src, dsq,
                                       Xb + 0, feature, IN_F,
                                       (const float*)nullptr, 0,
                                       X1f, Xb + IN_F, lambda_max, 1);
    k_gather<<<GBLK, 256, 0, stream>>>(row_start, csr_src, dsq,
                                       Xb + IN_F, X1f, IN_F,
                                       feature, IN_F,
                                       X2f, Xb + 2 * IN_F, lambda_max, 0);
    k_gather<<<GBLK, 256, 0, stream>>>(row_start, csr_src, dsq,
                                       Xb + 2 * IN_F, X2f, IN_F,
                                       X1f, IN_F,
                                       (float*)nullptr, Xb + 3 * IN_F, lambda_max, 0);

    // ---- eigen block ----
    k_ef<<<1, 128, 0, stream>>>(evals, ew0, eb0, ew1, eb1, ew2, eb2, ef);
    k_hs_partial<<<256, 256, 0, stream>>>(evecs, feature, hs_small);
    k_hs_apply<<<(N_NODES + 15) / 16, 128, 0, stream>>>(Xb, evecs, hs_small, ef);

    // ---- MFMA linear + BN + relu ----
    k_gemm<<<(N_NODES + 127) / 128, 256, 0, stream>>>(Xb, Wt, lin_b, out);
    k_bn_reduce<<<256, 256, 0, stream>>>(out, colsum, colsq);
    k_bn_apply<<<(N_NODES * 32) / 256, 256, 0, stream>>>(out, colsum, colsq, bn_gamma, bn_beta);
}

// Round 5
// 486.128 us; speedup vs baseline: 9.6267x; 1.3476x over previous
//
#include <hip/hip_runtime.h>

#define N_NODES 50000
#define N_EDGES 800000
#define IN_F    128
#define OUT_F   128
#define NEIG    64
#define HDIM    128
#define BN_EPSF 1e-5f
#define XB_ROWS 50048            // 50000 padded to 128
#define XB_COLS 640
#define SCAN_BLK 49              // ceil(50000/1024)
#define HSP_BLOCKS 521           // 521*96 >= 50000
#define HSP_NODES 96

typedef __attribute__((ext_vector_type(8))) short short8;
typedef __attribute__((ext_vector_type(4))) float floatx4;

// ---- workspace layout (in 4-byte units) ----
#define OFF_XB      0                                   // ushort[50048*640] -> 16,015,360 floats
#define OFF_X1F     (XB_ROWS * XB_COLS / 2)             // 16,015,360 (X1 fp32; later reused as hs partials)
#define OFF_X2F     (OFF_X1F + N_NODES * IN_F)          // 22,415,360
#define OFF_WT      (OFF_X2F + N_NODES * IN_F)          // 28,815,360 (ushort[640*128] = 40,960 floats)
#define OFF_DSQRT   (OFF_WT + 40960)                    // 28,856,320
#define OFF_HS      (OFF_DSQRT + N_NODES)
#define OFF_EF      (OFF_HS + NEIG * OUT_F)
#define OFF_COLSUM  (OFF_EF + NEIG)
#define OFF_COLSQ   (OFF_COLSUM + OUT_F)
#define OFF_DEG     (OFF_COLSQ + OUT_F)
#define OFF_ROWSTART (OFF_DEG + N_NODES)
#define OFF_CURSOR  (OFF_ROWSTART + N_NODES + 1)
#define OFF_CSR     (OFF_CURSOR + N_NODES)
#define OFF_BSUM    (OFF_CSR + N_EDGES)                 // 64 ints
// end ~= 29,914,865 floats ~= 119.7 MB (< 128.3 MB proven in R0)
// hs partials (521*8192 = 4.27M floats) live in the X1F region (6.4M), used only
// after the last gather has consumed X1f.

static __device__ inline unsigned short f2bf(float f) {
    union { float f; unsigned int u; } v; v.f = f;
    unsigned int r = (v.u + 0x7FFFu + ((v.u >> 16) & 1u)) >> 16;
    return (unsigned short)r;
}
static __device__ inline float bf2f(unsigned int u16) {
    union { unsigned int u; float f; } v; v.u = u16 << 16;
    return v.f;
}

__global__ void k_zero(int* __restrict__ deg, float* __restrict__ small) {
    int i = blockIdx.x * 256 + threadIdx.x;
    if (i < N_NODES) deg[i] = 0;
    if (i < NEIG * OUT_F + NEIG + 2 * OUT_F) small[i] = 0.0f;
}

__global__ void k_deg(int* __restrict__ deg, const int* __restrict__ dst) {
    int e = blockIdx.x * 256 + threadIdx.x;
    if (e < N_EDGES) atomicAdd(&deg[dst[e]], 1);
}

// ---- 3-stage parallel scan ----
__global__ __launch_bounds__(1024) void k_scan1(const int* __restrict__ deg,
                                                int* __restrict__ row_start,
                                                int* __restrict__ bsum) {
    __shared__ int sd[1024];
    int i = blockIdx.x * 1024 + threadIdx.x;
    int v = (i < N_NODES) ? deg[i] : 0;
    sd[threadIdx.x] = v;
    __syncthreads();
    for (int off = 1; off < 1024; off <<= 1) {
        int t = (threadIdx.x >= off) ? sd[threadIdx.x - off] : 0;
        __syncthreads();
        sd[threadIdx.x] += t;
        __syncthreads();
    }
    if (i < N_NODES) row_start[i] = sd[threadIdx.x] - v;
    if (threadIdx.x == 1023) bsum[blockIdx.x] = sd[1023];
}

__global__ void k_scan2(int* __restrict__ bsum) {
    int t = threadIdx.x;
    int orig = (t < SCAN_BLK) ? bsum[t] : 0;
    int v = orig;
    for (int off = 1; off < 64; off <<= 1) {
        int u = __shfl_up(v, off);
        if (t >= off) v += u;
    }
    if (t < SCAN_BLK) bsum[t] = v - orig;
}

__global__ __launch_bounds__(1024) void k_scan3(const int* __restrict__ deg,
                                                int* __restrict__ row_start,
                                                const int* __restrict__ bsum,
                                                int* __restrict__ cursor,
                                                float* __restrict__ dsq) {
    int i = blockIdx.x * 1024 + threadIdx.x;
    if (i < N_NODES) {
        int r = row_start[i] + bsum[blockIdx.x];
        row_start[i] = r;
        cursor[i] = r;
        dsq[i] = rsqrtf((float)max(deg[i], 1));
    }
    if (i == 0) row_start[N_NODES] = N_EDGES;
}

__global__ void k_bucket(const int* __restrict__ src, const int* __restrict__ dst,
                         int* __restrict__ cursor, int* __restrict__ csr_src) {
    int e = blockIdx.x * 256 + threadIdx.x;
    if (e < N_EDGES) {
        int d = dst[e];
        int pos = atomicAdd(&cursor[d], 1);
        csr_src[pos] = src[e];
    }
}

// feature fp32 -> Xb cols 0..127 (bf16)
__global__ void k_feat2bf(const float* __restrict__ feat, unsigned short* __restrict__ Xb) {
    int t = blockIdx.x * 256 + threadIdx.x;
    int n = t >> 4, c8 = (t & 15) * 8;
    float4 a = *(const float4*)&feat[n * IN_F + c8];
    float4 b = *(const float4*)&feat[n * IN_F + c8 + 4];
    ushort4 o0, o1;
    o0.x = f2bf(a.x); o0.y = f2bf(a.y); o0.z = f2bf(a.z); o0.w = f2bf(a.w);
    o1.x = f2bf(b.x); o1.y = f2bf(b.y); o1.z = f2bf(b.z); o1.w = f2bf(b.w);
    *(ushort4*)&Xb[(size_t)n * XB_COLS + c8]     = o0;
    *(ushort4*)&Xb[(size_t)n * XB_COLS + c8 + 4] = o1;
}

// W[640][128] fp32 -> Wt[128][640] bf16
__global__ void k_wt(const float* __restrict__ W, unsigned short* __restrict__ Wt) {
    int t = blockIdx.x * 256 + threadIdx.x;
    int k = t >> 7, n = t & 127;
    Wt[n * 640 + k] = f2bf(W[k * 128 + n]);
}

// One wave per node; 4x unrolled edge loop to keep 4 row-fetches in flight.
__global__ __launch_bounds__(256) void k_gather(const int* __restrict__ row_start,
                                                const int* __restrict__ csr_src,
                                                const float* __restrict__ dsq,
                                                const unsigned short* __restrict__ srcb,
                                                const float* __restrict__ prevmat, int prev_stride,
                                                const float* __restrict__ ppmat, int pp_stride,
                                                float* __restrict__ outf,
                                                unsigned short* __restrict__ outb,
                                                const float* __restrict__ lm, int first) {
    int n = (blockIdx.x * 256 + threadIdx.x) >> 6;
    int lane = threadIdx.x & 63;
    if (n >= N_NODES) return;
    float rn = 2.0f / lm[0];
    float ax = 0.0f, ay = 0.0f;
    int beg = row_start[n], end = row_start[n + 1];
    int i = beg;
    for (; i + 4 <= end; i += 4) {
        int s0 = __builtin_amdgcn_readfirstlane(csr_src[i]);
        int s1 = __builtin_amdgcn_readfirstlane(csr_src[i + 1]);
        int s2 = __builtin_amdgcn_readfirstlane(csr_src[i + 2]);
        int s3 = __builtin_amdgcn_readfirstlane(csr_src[i + 3]);
        float c0 = dsq[s0], c1 = dsq[s1], c2 = dsq[s2], c3 = dsq[s3];
        unsigned int p0 = *(const unsigned int*)&srcb[(size_t)s0 * XB_COLS + lane * 2];
        unsigned int p1 = *(const unsigned int*)&srcb[(size_t)s1 * XB_COLS + lane * 2];
        unsigned int p2 = *(const unsigned int*)&srcb[(size_t)s2 * XB_COLS + lane * 2];
        unsigned int p3 = *(const unsigned int*)&srcb[(size_t)s3 * XB_COLS + lane * 2];
        ax += c0 * bf2f(p0 & 0xffffu) + c1 * bf2f(p1 & 0xffffu)
            + c2 * bf2f(p2 & 0xffffu) + c3 * bf2f(p3 & 0xffffu);
        ay += c0 * bf2f(p0 >> 16) + c1 * bf2f(p1 >> 16)
            + c2 * bf2f(p2 >> 16) + c3 * bf2f(p3 >> 16);
    }
    for (; i < end; ++i) {
        int s = __builtin_amdgcn_readfirstlane(csr_src[i]);
        float sc = dsq[s];
        unsigned int pv = *(const unsigned int*)&srcb[(size_t)s * XB_COLS + lane * 2];
        ax += sc * bf2f(pv & 0xffffu);
        ay += sc * bf2f(pv >> 16);
    }
    float ds = dsq[n];
    float a = (first ? -rn : -2.0f * rn) * ds;
    float b = first ? (rn - 1.0f) : 2.0f * (rn - 1.0f);
    float2 pv = *(const float2*)&prevmat[(size_t)n * prev_stride + lane * 2];
    float rx = a * ax + b * pv.x;
    float ry = a * ay + b * pv.y;
    if (ppmat) {
        float2 pp = *(const float2*)&ppmat[(size_t)n * pp_stride + lane * 2];
        rx -= pp.x;
        ry -= pp.y;
    }
    if (outf) *(float2*)&outf[(size_t)n * IN_F + lane * 2] = make_float2(rx, ry);
    unsigned int packed = (unsigned int)f2bf(rx) | ((unsigned int)f2bf(ry) << 16);
    *(unsigned int*)&outb[(size_t)n * XB_COLS + lane * 2] = packed;
}

// eigen-MLP: 64 blocks (one per eigenvalue), 128 threads
__global__ __launch_bounds__(128) void k_ef2(const float* __restrict__ evals,
                                             const float* __restrict__ ew0,
                                             const float* __restrict__ eb0,
                                             const float* __restrict__ ew1,
                                             const float* __restrict__ eb1,
                                             const float* __restrict__ ew2,
                                             const float* __restrict__ eb2,
                                             float* __restrict__ ef) {
    __shared__ float z0[HDIM];
    __shared__ float red[HDIM];
    int i = blockIdx.x, j = threadIdx.x;
    float ev = evals[i];
    z0[j] = fmaxf(0.0f, ev * ew0[j] + eb0[j]);
    __syncthreads();
    float s0 = 0.f, s1 = 0.f, s2 = 0.f, s3 = 0.f;
    for (int h = 0; h < HDIM; h += 4) {
        s0 += z0[h]     * ew1[(h) * HDIM + j];
        s1 += z0[h + 1] * ew1[(h + 1) * HDIM + j];
        s2 += z0[h + 2] * ew1[(h + 2) * HDIM + j];
        s3 += z0[h + 3] * ew1[(h + 3) * HDIM + j];
    }
    float z1 = fmaxf(0.0f, eb1[j] + s0 + s1 + s2 + s3);
    red[j] = z1 * ew2[j];
    __syncthreads();
    for (int off = 64; off > 0; off >>= 1) {
        if (j < off) red[j] += red[j + off];
        __syncthreads();
    }
    if (j == 0) ef[i] = red[0] + eb2[0];
}

// hs partial: block b handles 96 nodes; partial C[64][128] -> partials[b]
__global__ __launch_bounds__(256) void k_hs_partial2(const float* __restrict__ evecs,
                                                     const float* __restrict__ feat,
                                                     float* __restrict__ partials) {
    __shared__ float sEv[32 * NEIG];    // 8 KB
    __shared__ float sFt[32 * IN_F];    // 16 KB
    int t = threadIdx.x;
    int e0 = (t >> 5) * 8;      // 8 eigen rows
    int f0 = (t & 31) * 4;      // 4 feature cols
    float acc[8][4];
#pragma unroll
    for (int r = 0; r < 8; ++r)
#pragma unroll
        for (int c = 0; c < 4; ++c) acc[r][c] = 0.0f;

    int n0 = blockIdx.x * HSP_NODES;
    for (int ch = 0; ch < HSP_NODES; ch += 32) {
        int base = n0 + ch;
        // stage evecs 32x64
        {
            int r = t >> 3, c = (t & 7) * 8;
            int n = base + r;
            float4 a, b;
            if (n < N_NODES) {
                a = *(const float4*)&evecs[(size_t)n * NEIG + c];
                b = *(const float4*)&evecs[(size_t)n * NEIG + c + 4];
            } else {
                a = make_float4(0, 0, 0, 0); b = a;
            }
            *(float4*)&sEv[r * NEIG + c] = a;
            *(float4*)&sEv[r * NEIG + c + 4] = b;
        }
        // stage feature 32x128
        {
            int r = t >> 3, c = (t & 7) * 16;
            int n = base + r;
#pragma unroll
            for (int q = 0; q < 4; ++q) {
                float4 v = (n < N_NODES) ? *(const float4*)&feat[(size_t)n * IN_F + c + q * 4]
                                         : make_float4(0, 0, 0, 0);
                *(float4*)&sFt[r * IN_F + c + q * 4] = v;
            }
        }
        __syncthreads();
#pragma unroll 2
        for (int i = 0; i < 32; ++i) {
            float4 ev0 = *(float4*)&sEv[i * NEIG + e0];
            float4 ev1 = *(float4*)&sEv[i * NEIG + e0 + 4];
            float4 fv  = *(float4*)&sFt[i * IN_F + f0];
            float evv[8] = {ev0.x, ev0.y, ev0.z, ev0.w, ev1.x, ev1.y, ev1.z, ev1.w};
#pragma unroll
            for (int r = 0; r < 8; ++r) {
                acc[r][0] += evv[r] * fv.x;
                acc[r][1] += evv[r] * fv.y;
                acc[r][2] += evv[r] * fv.z;
                acc[r][3] += evv[r] * fv.w;
            }
        }
        __syncthreads();
    }
    float* p = &partials[(size_t)blockIdx.x * (NEIG * IN_F)];
#pragma unroll
    for (int r = 0; r < 8; ++r)
        *(float4*)&p[(e0 + r) * IN_F + f0] = make_float4(acc[r][0], acc[r][1], acc[r][2], acc[r][3]);
}

// reduce partials -> hs_small
__global__ void k_hs_reduce(const float* __restrict__ partials, float* __restrict__ hs_small) {
    int p = blockIdx.x * 256 + threadIdx.x;   // 8192 threads
    float s = 0.0f;
    for (int j = 0; j < HSP_BLOCKS; ++j) s += partials[(size_t)j * (NEIG * IN_F) + p];
    hs_small[p] = s;
}

// Xb[n, 512+f] = bf16( sum_e evecs[n,e] * ef[e] * hs_small[e,f] ); 32 nodes/block
__global__ __launch_bounds__(256) void k_hs_apply2(unsigned short* __restrict__ Xb,
                                                   const float* __restrict__ evecs,
                                                   const float* __restrict__ hs_small,
                                                   const float* __restrict__ ef) {
    __shared__ float sShs[NEIG * HDIM];   // 32 KB
    __shared__ float sEv[32 * NEIG];      // 8 KB
    int t = threadIdx.x;
    int n0 = blockIdx.x * 32;
    // stage shs = ef[e] * hs_small[e][f]
    {
        float efv = ef[t >> 2];           // row e = (t*32)>>7 = t>>2
        int pbase = t * 32;
#pragma unroll
        for (int q = 0; q < 8; ++q) {
            float4 v = *(const float4*)&hs_small[pbase + q * 4];
            v.x *= efv; v.y *= efv; v.z *= efv; v.w *= efv;
            *(float4*)&sShs[pbase + q * 4] = v;
        }
    }
    // stage evecs 32x64
    {
        int r = t >> 3, c = (t & 7) * 8;
        int n = n0 + r;
        float4 a, b;
        if (n < N_NODES) {
            a = *(const float4*)&evecs[(size_t)n * NEIG + c];
            b = *(const float4*)&evecs[(size_t)n * NEIG + c + 4];
        } else {
            a = make_float4(0, 0, 0, 0); b = a;
        }
        *(float4*)&sEv[r * NEIG + c] = a;
        *(float4*)&sEv[r * NEIG + c + 4] = b;
    }
    __syncthreads();
    int nb = (t >> 5) * 4;      // 4 nodes
    int f0 = (t & 31) * 4;      // 4 cols
    float acc[4][4];
#pragma unroll
    for (int q = 0; q < 4; ++q)
#pragma unroll
        for (int c = 0; c < 4; ++c) acc[q][c] = 0.0f;
    for (int e = 0; e < NEIG; ++e) {
        float4 sv = *(float4*)&sShs[e * HDIM + f0];
#pragma unroll
        for (int q = 0; q < 4; ++q) {
            float evv = sEv[(nb + q) * NEIG + e];
            acc[q][0] += evv * sv.x;
            acc[q][1] += evv * sv.y;
            acc[q][2] += evv * sv.z;
            acc[q][3] += evv * sv.w;
        }
    }
#pragma unroll
    for (int q = 0; q < 4; ++q) {
        int n = n0 + nb + q;
        if (n < N_NODES) {
            ushort4 o;
            o.x = f2bf(acc[q][0]); o.y = f2bf(acc[q][1]);
            o.z = f2bf(acc[q][2]); o.w = f2bf(acc[q][3]);
            *(ushort4*)&Xb[(size_t)n * XB_COLS + 4 * IN_F + f0] = o;
        }
    }
}

// MFMA bf16 GEMM
__global__ __launch_bounds__(256) void k_gemm(const unsigned short* __restrict__ Xb,
                                              const unsigned short* __restrict__ Wt,
                                              const float* __restrict__ bias,
                                              float* __restrict__ out) {
    __shared__ unsigned short sA[128 * 32];
    __shared__ unsigned short sB[128 * 32];
    int tid = threadIdx.x;
    int wave = tid >> 6, lane = tid & 63;
    int quad = lane >> 4, m16 = lane & 15;
    int row0 = blockIdx.x * 128;

    floatx4 acc[2][8];
#pragma unroll
    for (int mt = 0; mt < 2; ++mt)
#pragma unroll
        for (int nt = 0; nt < 8; ++nt) acc[mt][nt] = (floatx4)(0.0f);

    int r  = tid >> 2;
    int c8 = (tid & 3) * 8;
    int gr0 = min(row0 + r, N_NODES - 1);
    int gr1 = min(row0 + r + 64, N_NODES - 1);

    for (int k0 = 0; k0 < 640; k0 += 32) {
        *(uint4*)&sA[r * 32 + c8]        = *(const uint4*)&Xb[(size_t)gr0 * XB_COLS + k0 + c8];
        *(uint4*)&sA[(r + 64) * 32 + c8] = *(const uint4*)&Xb[(size_t)gr1 * XB_COLS + k0 + c8];
        *(uint4*)&sB[r * 32 + c8]        = *(const uint4*)&Wt[r * 640 + k0 + c8];
        *(uint4*)&sB[(r + 64) * 32 + c8] = *(const uint4*)&Wt[(r + 64) * 640 + k0 + c8];
        __syncthreads();
        short8 a0 = *(short8*)&sA[(wave * 32 + m16) * 32 + quad * 8];
        short8 a1 = *(short8*)&sA[(wave * 32 + 16 + m16) * 32 + quad * 8];
#pragma unroll
        for (int nt = 0; nt < 8; ++nt) {
            short8 b = *(short8*)&sB[(nt * 16 + m16) * 32 + quad * 8];
            acc[0][nt] = __builtin_amdgcn_mfma_f32_16x16x32_bf16(a0, b, acc[0][nt], 0, 0, 0);
            acc[1][nt] = __builtin_amdgcn_mfma_f32_16x16x32_bf16(a1, b, acc[1][nt], 0, 0, 0);
        }
        __syncthreads();
    }
#pragma unroll
    for (int mt = 0; mt < 2; ++mt) {
        int rbase = row0 + wave * 32 + mt * 16 + quad * 4;
#pragma unroll
        for (int nt = 0; nt < 8; ++nt) {
            int col = nt * 16 + m16;
            float bb = bias[col];
#pragma unroll
            for (int reg = 0; reg < 4; ++reg) {
                int row = rbase + reg;
                if (row < N_NODES) out[(size_t)row * OUT_F + col] = acc[mt][nt][reg] + bb;
            }
        }
    }
}

__global__ void k_bn_reduce(const float* __restrict__ out, float* __restrict__ colsum,
                            float* __restrict__ colsq) {
    int f = threadIdx.x & 127, half = threadIdx.x >> 7;
    float s = 0.0f, sq = 0.0f;
    for (int n = blockIdx.x * 2 + half; n < N_NODES; n += gridDim.x * 2) {
        float v = out[n * OUT_F + f];
        s += v; sq += v * v;
    }
    __shared__ float ls[256], lq[256];
    ls[threadIdx.x] = s; lq[threadIdx.x] = sq;
    __syncthreads();
    if (half == 0) {
        atomicAdd(&colsum[f], ls[f] + ls[128 + f]);
        atomicAdd(&colsq[f], lq[f] + lq[128 + f]);
    }
}

__global__ void k_bn_apply(float* __restrict__ out, const float* __restrict__ colsum,
                           const float* __restrict__ colsq, const float* __restrict__ gamma,
                           const float* __restrict__ beta) {
    int t = blockIdx.x * 256 + threadIdx.x;
    int n = t >> 5, c = t & 31;
    float4 v = *(float4*)&out[n * OUT_F + c * 4];
    float4 s = *(const float4*)&colsum[c * 4];
    float4 q = *(const float4*)&colsq[c * 4];
    float4 g = *(const float4*)&gamma[c * 4];
    float4 b = *(const float4*)&beta[c * 4];
    const float invN = 1.0f / (float)N_NODES;
    float mux = s.x * invN, muy = s.y * invN, muz = s.z * invN, muw = s.w * invN;
    float ix = rsqrtf(q.x * invN - mux * mux + BN_EPSF);
    float iy = rsqrtf(q.y * invN - muy * muy + BN_EPSF);
    float iz = rsqrtf(q.z * invN - muz * muz + BN_EPSF);
    float iw = rsqrtf(q.w * invN - muw * muw + BN_EPSF);
    v.x = fmaxf(0.0f, (v.x - mux) * ix * g.x + b.x);
    v.y = fmaxf(0.0f, (v.y - muy) * iy * g.y + b.y);
    v.z = fmaxf(0.0f, (v.z - muz) * iz * g.z + b.z);
    v.w = fmaxf(0.0f, (v.w - muw) * iw * g.w + b.w);
    *(float4*)&out[n * OUT_F + c * 4] = v;
}

extern "C" void kernel_launch(void* const* d_in, const int* in_sizes, int n_in,
                              void* d_out, int out_size, void* d_ws, size_t ws_size,
                              hipStream_t stream) {
    const float* feature    = (const float*)d_in[0];
    const float* lin_w      = (const float*)d_in[1];
    const float* lin_b      = (const float*)d_in[2];
    const float* ew0        = (const float*)d_in[3];
    const float* eb0        = (const float*)d_in[4];
    const float* ew1        = (const float*)d_in[5];
    const float* eb1        = (const float*)d_in[6];
    const float* ew2        = (const float*)d_in[7];
    const float* eb2        = (const float*)d_in[8];
    const float* bn_gamma   = (const float*)d_in[9];
    const float* bn_beta    = (const float*)d_in[10];
    const float* lambda_max = (const float*)d_in[11];
    const float* evecs      = (const float*)d_in[12];
    const float* evals      = (const float*)d_in[13];
    const int*   edge_src   = (const int*)d_in[14];
    const int*   edge_dst   = (const int*)d_in[15];

    float* out = (float*)d_out;
    float* ws  = (float*)d_ws;
    unsigned short* Xb = (unsigned short*)(ws + OFF_XB);
    float* X1f      = ws + OFF_X1F;
    float* X2f      = ws + OFF_X2F;
    unsigned short* Wt = (unsigned short*)(ws + OFF_WT);
    float* dsq      = ws + OFF_DSQRT;
    float* hs_small = ws + OFF_HS;
    float* ef       = ws + OFF_EF;
    float* colsum   = ws + OFF_COLSUM;
    float* colsq    = ws + OFF_COLSQ;
    int*   deg      = (int*)(ws + OFF_DEG);
    int*   row_start= (int*)(ws + OFF_ROWSTART);
    int*   cursor   = (int*)(ws + OFF_CURSOR);
    int*   csr_src  = (int*)(ws + OFF_CSR);
    int*   bsum     = (int*)(ws + OFF_BSUM);
    float* partials = ws + OFF_X1F;   // reuse X1f region after gathers are done

    // ---- CSR build + conversions ----
    k_zero<<<229, 256, 0, stream>>>(deg, hs_small);
    k_deg<<<(N_EDGES + 255) / 256, 256, 0, stream>>>(deg, edge_dst);
    k_feat2bf<<<(N_NODES * 16 + 255) / 256, 256, 0, stream>>>(feature, Xb);
    k_wt<<<320, 256, 0, stream>>>(lin_w, Wt);
    k_scan1<<<SCAN_BLK, 1024, 0, stream>>>(deg, row_start, bsum);
    k_scan2<<<1, 64, 0, stream>>>(bsum);
    k_scan3<<<SCAN_BLK, 1024, 0, stream>>>(deg, row_start, bsum, cursor, dsq);
    k_bucket<<<(N_EDGES + 255) / 256, 256, 0, stream>>>(edge_src, edge_dst, cursor, csr_src);

    // ---- Chebyshev recurrence ----
    const int GBLK = (N_NODES * 64 + 255) / 256;
    k_gather<<<GBLK, 256, 0, stream>>>(row_start, csr_src, dsq,
                                       Xb + 0, feature, IN_F,
                                       (const float*)nullptr, 0,
                                       X1f, Xb + IN_F, lambda_max, 1);
    k_gather<<<GBLK, 256, 0, stream>>>(row_start, csr_src, dsq,
                                       Xb + IN_F, X1f, IN_F,
                                       feature, IN_F,
                                       X2f, Xb + 2 * IN_F, lambda_max, 0);
    k_gather<<<GBLK, 256, 0, stream>>>(row_start, csr_src, dsq,
                                       Xb + 2 * IN_F, X2f, IN_F,
                                       X1f, IN_F,
                                       (float*)nullptr, Xb + 3 * IN_F, lambda_max, 0);

    // ---- eigen block (X1f region is dead now; reuse for partials) ----
    k_ef2<<<NEIG, 128, 0, stream>>>(evals, ew0, eb0, ew1, eb1, ew2, eb2, ef);
    k_hs_partial2<<<HSP_BLOCKS, 256, 0, stream>>>(evecs, feature, partials);
    k_hs_reduce<<<32, 256, 0, stream>>>(partials, hs_small);
    k_hs_apply2<<<(N_NODES + 31) / 32, 256, 0, stream>>>(Xb, evecs, hs_small, ef);

    // ---- MFMA linear + BN + relu ----
    k_gemm<<<(N_NODES + 127) / 128, 256, 0, stream>>>(Xb, Wt, lin_b, out);
    k_bn_reduce<<<256, 256, 0, stream>>>(out, colsum, colsq);
    k_bn_apply<<<(N_NODES * 32) / 256, 256, 0, stream>>>(out, colsum, colsq, bn_gamma, bn_beta);
}